// Round 2
// baseline (898.768 us; speedup 1.0000x reference)
//
#include <hip/hip_runtime.h>
#include <math.h>

#define DEVINL __device__ __forceinline__

constexpr int B_ = 64;
constexpr int N_ = 3136;
constexpr int C_ = 64;        // DIM
constexpr int NG = 49;        // N_grid
constexpr int NSAMP = 784;    // SAMPLE_NUM
constexpr int ND = NG + NSAMP;     // 833
constexpr int NREST = N_ - NG;     // 3087
constexpr int H_ = 56, W_ = 56;
constexpr int HW = H_ * W_;        // 3136
constexpr int BHW = B_ * HW;       // 200704
constexpr int NS = 14 * 14;        // 196 kv tokens
constexpr int KPAD = 224;          // 196 padded to 7*32
constexpr float LN_EPS = 1e-5f;
constexpr float EPS6 = 1e-6f;

typedef __attribute__((ext_vector_type(8))) short short8;
typedef __attribute__((ext_vector_type(4))) float f32x4;

DEVINL unsigned short f2bf(float f) {
  unsigned int u = __float_as_uint(f);
  unsigned int r = u + 0x7FFFu + ((u >> 16) & 1u);
  return (unsigned short)(r >> 16);
}

// ---------------------------------------------------------------------------
// K1: conf scores in FP64 (discrete top-k decision must match f64 np ref)
// ---------------------------------------------------------------------------
__global__ __launch_bounds__(256) void k_conf(
    const float* __restrict__ x, const float* __restrict__ ng, const float* __restrict__ nb,
    const float* __restrict__ cw, const float* __restrict__ cb,
    const float* __restrict__ nu, double* __restrict__ scores) {
  int t = blockIdx.x * 256 + threadIdx.x;
  if (t >= B_ * N_) return;
  int b = t / N_, n = t - b * N_;
  if (n < NG) return;
  const float4* row = (const float4*)(x + (size_t)t * C_);
  float v[C_];
#pragma unroll
  for (int i = 0; i < 16; ++i) {
    float4 r = row[i];
    v[4*i] = r.x; v[4*i+1] = r.y; v[4*i+2] = r.z; v[4*i+3] = r.w;
  }
  double sd = 0.0;
#pragma unroll
  for (int i = 0; i < C_; ++i) sd += (double)v[i];
  double md = sd * (1.0/64.0);
  double vd = 0.0;
#pragma unroll
  for (int i = 0; i < C_; ++i) { double d = (double)v[i] - md; vd += d * d; }
  vd *= (1.0/64.0);
  double rsd = 1.0 / sqrt(vd + 1e-5);
  double conf = (double)cb[0];
#pragma unroll
  for (int i = 0; i < C_; ++i) {
    double xnv = ((double)v[i] - md) * rsd;
    conf += (xnv * (double)ng[i] + (double)nb[i]) * (double)cw[i];
  }
  double u = (double)nu[(size_t)b * NREST + (n - NG)];
  double noise = -log(-log(u + 1e-6) + 1e-6);
  scores[(size_t)b * NREST + (n - NG)] = conf + noise;
}

// ---------------------------------------------------------------------------
// K2 (ROUND-8): top-784 via rank-by-count. rank(i) = #{j: k_j > k_i} +
// #{j: k_j == k_i && j < i}. Ranks are a permutation of 0..3086, so writing
// idx[rank]=i for rank<784 yields exactly jax.lax.top_k order (descending
// score, ties by ascending index). Keys LDS-resident; inner loop reads are
// wave-uniform broadcasts. 448 blocks (vs 64) and a single barrier (vs 78).
// ---------------------------------------------------------------------------
constexpr int RCHUNK = 512;          // elements per block
constexpr int NCHUNK = (NREST + RCHUNK - 1) / RCHUNK;   // 7

__global__ __launch_bounds__(256) void k_rank(const double* __restrict__ scores,
                                              int* __restrict__ idx) {
  __shared__ unsigned long long ls[NREST];   // 24,696 B
  int blk = blockIdx.x;
  int b = blk / NCHUNK, ch = blk - b * NCHUNK;
  const double* sc = scores + (size_t)b * NREST;
  for (int i = threadIdx.x; i < NREST; i += 256) {
    long long bits = __double_as_longlong(sc[i]);
    unsigned long long ub = (unsigned long long)bits;
    ls[i] = (bits < 0) ? ~ub : (ub | 0x8000000000000000ULL);  // monotone map
  }
  __syncthreads();
  int e0 = ch * RCHUNK + threadIdx.x;
  int e1 = e0 + 256;
  unsigned long long k0 = (e0 < NREST) ? ls[e0] : 0ULL;
  unsigned long long k1 = (e1 < NREST) ? ls[e1] : 0ULL;
  int c0 = 0, c1 = 0;
#pragma unroll 4
  for (int j = 0; j < NREST; ++j) {
    unsigned long long kj = ls[j];
    c0 += (int)((kj > k0) | ((kj == k0) & (j < e0)));
    c1 += (int)((kj > k1) | ((kj == k1) & (j < e1)));
  }
  if (e0 < NREST && c0 < NSAMP) idx[(size_t)b * NSAMP + c0] = e0;
  if (e1 < NREST && c1 < NSAMP) idx[(size_t)b * NSAMP + c1] = e1;
}

// ---------------------------------------------------------------------------
// K3: gather x_down/pos_down rows; LayerNorm(x_down, norm1) -> xn
// ---------------------------------------------------------------------------
__global__ __launch_bounds__(256) void k_gather_ln(
    const float* __restrict__ x, const float* __restrict__ pos, const int* __restrict__ idx,
    const float* __restrict__ n1g, const float* __restrict__ n1b,
    float* __restrict__ xd, float* __restrict__ xn, float* __restrict__ pd) {
  int t = blockIdx.x * 256 + threadIdx.x;
  if (t >= B_ * ND) return;
  int b = t / ND, r = t - b * ND;
  int srcn = (r < NG) ? r : (NG + idx[(size_t)b * NSAMP + (r - NG)]);
  const float4* row = (const float4*)(x + ((size_t)b * N_ + srcn) * C_);
  float4* xdr = (float4*)(xd + (size_t)t * C_);
  float v[C_];
  float s = 0.f, ss = 0.f;
#pragma unroll
  for (int i = 0; i < 16; ++i) {
    float4 rr = row[i];
    xdr[i] = rr;
    v[4*i] = rr.x; v[4*i+1] = rr.y; v[4*i+2] = rr.z; v[4*i+3] = rr.w;
    s += rr.x + rr.y + rr.z + rr.w;
    ss += rr.x*rr.x + rr.y*rr.y + rr.z*rr.z + rr.w*rr.w;
  }
  float m = s * (1.f/64.f);
  float var = ss * (1.f/64.f) - m*m;
  float rs = rsqrtf(var + LN_EPS);
#pragma unroll
  for (int i = 0; i < C_; ++i)
    xn[(size_t)t * C_ + i] = (v[i] - m) * rs * n1g[i] + n1b[i];
  pd[(size_t)2*t]   = pos[((size_t)b * N_ + srcn) * 2];
  pd[(size_t)2*t+1] = pos[((size_t)b * N_ + srcn) * 2 + 1];
}

// ---------------------------------------------------------------------------
// K4: scatter: one WAVE per token, lane = channel; coalesced atomics.
// ---------------------------------------------------------------------------
__global__ __launch_bounds__(256) void k_scatter(
    const float* __restrict__ x, const float* __restrict__ n1g, const float* __restrict__ n1b,
    const float* __restrict__ pos, float* __restrict__ S) {
  int gt = blockIdx.x * 256 + threadIdx.x;
  int tok = gt >> 6, lane = gt & 63;
  if (tok >= B_ * N_) return;
  int b = tok / N_;
  float v = x[(size_t)tok * C_ + lane];
  float s = v, ss = v * v;
#pragma unroll
  for (int m = 32; m > 0; m >>= 1) {
    s += __shfl_xor(s, m);
    ss += __shfl_xor(ss, m);
  }
  float mean = s * (1.f/64.f);
  float var = ss * (1.f/64.f) - mean * mean;
  float rs = rsqrtf(var + LN_EPS);
  double px = fmin(fmax((double)pos[(size_t)2*tok],   0.0), 1.0) * (double)(W_ - 1);
  double py = fmin(fmax((double)pos[(size_t)2*tok+1], 0.0), 1.0) * (double)(H_ - 1);
  int xi = (int)rint(px), yi = (int)rint(py);
  float* base = S + ((size_t)b * HW + yi * W_ + xi) * 65;
  atomicAdd(base + lane, (v - mean) * rs * n1g[lane] + n1b[lane]);
  if (lane == 0) atomicAdd(base + 64, 1.f);
}

// ---------------------------------------------------------------------------
// K5a: per-pixel 3x3 coefficient planes from the mask channel.
// ---------------------------------------------------------------------------
__global__ __launch_bounds__(256) void k_coef(const float* __restrict__ S, float* __restrict__ Kc) {
  int t = blockIdx.x * 256 + threadIdx.x;
  if (t >= BHW) return;
  int b = t / HW, p = t - b * HW;
  int y = p / W_, x = p - y * W_;
  const float* Sb = S + (size_t)b * HW * 65;
  const float e1 = 0.882496902584595f;   // exp(-1/8)
  const float e2 = 0.778800783071405f;   // exp(-1/4)
  const float Z = 1.f + 4.f * (e1 + e2);
  float m0 = Sb[(size_t)p * 65 + 64];
  float mb0 = m0 > 0.f ? 1.f : 0.f;
  float cfac = mb0 / (m0 + EPS6);
  float sc[9];
  float mi = 0.f;
  int q = 0;
#pragma unroll
  for (int dy = -1; dy <= 1; ++dy) {
#pragma unroll
    for (int dx = -1; dx <= 1; ++dx) {
      int ny = y + dy, nx = x + dx;
      bool in = (ny >= 0 && ny < H_ && nx >= 0 && nx < W_);
      float w = ((dx == 0 && dy == 0) ? 1.f : ((dx*dx + dy*dy) == 1 ? e1 : e2)) / Z;
      float mm = in ? Sb[(size_t)(ny * W_ + nx) * 65 + 64] : 0.f;
      float mb = mm > 0.f ? 1.f : 0.f;
      mi += w * mb;
      sc[q] = in ? (w * mb / (mm + EPS6)) : 0.f;
      ++q;
    }
  }
  float outer = (1.f - mb0) * ((mi > 0.f ? 1.f : 0.f) / (mi + EPS6));
#pragma unroll
  for (int qq = 0; qq < 9; ++qq) {
    float cq = outer * sc[qq];
    if (qq == 4) cq += cfac;
    Kc[(size_t)qq * BHW + t] = cq;
  }
}

// ---------------------------------------------------------------------------
// K5b: transpose S[p][65] -> channel-major planes T[b][c][HW].
// ---------------------------------------------------------------------------
__global__ __launch_bounds__(256) void k_transpose(const float* __restrict__ S, float* __restrict__ T) {
  __shared__ float ls[64 * 65];
  int g0 = blockIdx.x * 64;            // global pixel base (batch-major)
  int b = g0 / HW, p0 = g0 - b * HW;
  const float4* src = (const float4*)(S + (size_t)g0 * 65);
  for (int i = threadIdx.x; i < (64 * 65) / 4; i += 256)
    *(float4*)&ls[i * 4] = src[i];
  __syncthreads();
  for (int i = threadIdx.x; i < 64 * 64; i += 256) {
    int c = i >> 6, px = i & 63;
    T[((size_t)(b * 64 + c)) * HW + p0 + px] = ls[px * 65 + c];
  }
}

// ---------------------------------------------------------------------------
// K5c: spatially-varying 3x3 conv on channel planes -> conv-patch layout P.
// ---------------------------------------------------------------------------
__global__ __launch_bounds__(256) void k_filter2(
    const float* __restrict__ T, const float* __restrict__ Kc, float* __restrict__ P) {
  int plane = blockIdx.x;              // b*64 + c
  int b = plane >> 6, c = plane & 63;
  int tid = threadIdx.x;
  const float* Tp = T + (size_t)plane * HW;
  const float* Kb = Kc + (size_t)b * HW;
  for (int p0 = 0; p0 < HW; p0 += 256) {
    int p = p0 + tid;
    if (p < HW) {
      int y = p / W_, x = p - y * W_;
      float acc = 0.f;
      int q = 0;
#pragma unroll
      for (int dy = -1; dy <= 1; ++dy) {
#pragma unroll
        for (int dx = -1; dx <= 1; ++dx) {
          int ny = y + dy; ny = ny < 0 ? 0 : (ny > H_ - 1 ? H_ - 1 : ny);
          int nx = x + dx; nx = nx < 0 ? 0 : (nx > W_ - 1 ? W_ - 1 : nx);
          acc += Kb[(size_t)q * BHW + p] * Tp[ny * W_ + nx];
          ++q;
        }
      }
      int j = (y >> 2) * 14 + (x >> 2);
      int colb = ((y & 3) << 2) + (x & 3);
      P[((size_t)(b * NS + j)) * 1024 + c * 16 + colb] = acc;
    }
  }
}

// ---------------------------------------------------------------------------
// K6: transpose sr_w (co,ci,ky,kx) -> w_t[kk=ci*16+ky*4+kx][co]
// ---------------------------------------------------------------------------
__global__ __launch_bounds__(256) void k_wt(const float* __restrict__ srw, float* __restrict__ wt) {
  int t = blockIdx.x * 256 + threadIdx.x;
  if (t >= 1024 * 64) return;
  int kk = t >> 6, co = t & 63;
  int ci = kk >> 4, r = kk & 15;
  wt[t] = srw[(((size_t)co * 64 + ci) << 4) + r];
}

// ---------------------------------------------------------------------------
// K6b: pack fc1/fc2 weights into B-frag-contiguous bf16 layout
// ---------------------------------------------------------------------------
__global__ __launch_bounds__(256) void k_wpack(const float* __restrict__ W1, const float* __restrict__ W2,
    unsigned short* __restrict__ W1p, unsigned short* __restrict__ W2p) {
  int t = blockIdx.x * 256 + threadIdx.x;
  if (t >= 65536) return;
  {
    int j = t & 7;
    int n = (t >> 3) & 511;
    int qk = t >> 12;            // 0..15
    int quad = qk & 3, kc = qk >> 2;
    int k = kc * 32 + quad * 8 + j;
    W1p[t] = f2bf(W1[(size_t)k * 512 + n]);
  }
  {
    int j = t & 7;
    int n = (t >> 3) & 127;
    int qk = t >> 10;            // 0..63
    int quad = qk & 3, kg = qk >> 2;
    int k = kg * 32 + quad * 8 + j;
    W2p[t] = f2bf(W2[(size_t)k * 128 + n]);
  }
}

// ---------------------------------------------------------------------------
// Tiled fp32 GEMM: C[M,N] = A[M,K] @ B[K,N] (+bias)(+add)
// ---------------------------------------------------------------------------
__global__ __launch_bounds__(256) void k_gemm(
    const float* __restrict__ A, const float* __restrict__ Bw,
    const float* __restrict__ bias, const float* __restrict__ add,
    float* __restrict__ Cout, int M, int N, int K) {
  __shared__ float sA[16][68];
  __shared__ float sB[16][64];
  int bm = blockIdx.x * 64, bn = blockIdx.y * 64;
  int tid = threadIdx.x;
  int tx = tid & 15, ty = tid >> 4;
  float acc[4][4] = {{0.f}};
  for (int k0 = 0; k0 < K; k0 += 16) {
    int e = tid << 2;
    int am = e >> 4, ak = e & 15;
    float4 a4 = *(const float4*)(A + (size_t)(bm + am) * K + k0 + ak);
    sA[ak + 0][am] = a4.x; sA[ak + 1][am] = a4.y; sA[ak + 2][am] = a4.z; sA[ak + 3][am] = a4.w;
    int bk = e >> 6, nn = e & 63;
    float4 b4 = *(const float4*)(Bw + (size_t)(k0 + bk) * N + bn + nn);
    *(float4*)&sB[bk][nn] = b4;
    __syncthreads();
#pragma unroll
    for (int kk = 0; kk < 16; ++kk) {
      float a[4], bb[4];
#pragma unroll
      for (int i = 0; i < 4; ++i) a[i] = sA[kk][ty * 4 + i];
#pragma unroll
      for (int i = 0; i < 4; ++i) bb[i] = sB[kk][tx * 4 + i];
#pragma unroll
      for (int i = 0; i < 4; ++i)
#pragma unroll
        for (int jj = 0; jj < 4; ++jj) acc[i][jj] += a[i] * bb[jj];
    }
    __syncthreads();
  }
#pragma unroll
  for (int i = 0; i < 4; ++i) {
    int row = bm + ty * 4 + i;
#pragma unroll
    for (int jj = 0; jj < 4; ++jj) {
      int col = bn + tx * 4 + jj;
      float v = acc[i][jj];
      if (bias) v += bias[col];
      if (add) v += add[(size_t)row * N + col];
      Cout[(size_t)row * N + col] = v;
    }
  }
}

// ---------------------------------------------------------------------------
// K-MLP: MFMA bf16. out += gelu(A@W1+b1)@W2+b2.
// ---------------------------------------------------------------------------
__global__ __launch_bounds__(256) void k_mlp(
    const float* __restrict__ A, const unsigned short* __restrict__ W1p, const float* __restrict__ b1,
    const unsigned short* __restrict__ W2p, const float* __restrict__ b2, float* __restrict__ out) {
  __shared__ __align__(16) unsigned short sA[64 * 128];
  __shared__ __align__(16) unsigned short sH[4][16 * 128];
  int bm = blockIdx.x * 64;
  int tid = threadIdx.x;
  int wv = tid >> 6, lane = tid & 63, quad = lane >> 4, l16 = lane & 15;

  for (int t = tid; t < 64 * 16; t += 256) {
    int row = t >> 4, ck = t & 15;
    const float* src = A + (size_t)(bm + row) * 128 + ck * 8;
    float4 a = *(const float4*)src;
    float4 c = *(const float4*)(src + 4);
    short8 p;
    p[0]=(short)f2bf(a.x); p[1]=(short)f2bf(a.y); p[2]=(short)f2bf(a.z); p[3]=(short)f2bf(a.w);
    p[4]=(short)f2bf(c.x); p[5]=(short)f2bf(c.y); p[6]=(short)f2bf(c.z); p[7]=(short)f2bf(c.w);
    *(short8*)&sA[row * 128 + (((ck ^ row) & 15) << 3)] = p;
  }
  __syncthreads();

  f32x4 oacc[8];
#pragma unroll
  for (int ct = 0; ct < 8; ++ct) oacc[ct] = (f32x4){0.f, 0.f, 0.f, 0.f};

  for (int hc = 0; hc < 4; ++hc) {
    f32x4 acc1[8];
#pragma unroll
    for (int ct = 0; ct < 8; ++ct) acc1[ct] = (f32x4){0.f, 0.f, 0.f, 0.f};
#pragma unroll
    for (int kc = 0; kc < 4; ++kc) {
      int row = wv * 16 + l16;
      int ck = kc * 4 + quad;
      short8 af = *(const short8*)&sA[row * 128 + (((ck ^ row) & 15) << 3)];
#pragma unroll
      for (int ct = 0; ct < 8; ++ct) {
        int n = hc * 128 + ct * 16 + l16;
        short8 bf = *(const short8*)&W1p[(((size_t)kc * 4 + quad) * 512 + n) << 3];
        acc1[ct] = __builtin_amdgcn_mfma_f32_16x16x32_bf16(af, bf, acc1[ct], 0, 0, 0);
      }
    }
    __syncthreads();   // prior GEMM2 reads of sH done (all waves)
#pragma unroll
    for (int ct = 0; ct < 8; ++ct)
#pragma unroll
      for (int r = 0; r < 4; ++r) {
        float v = acc1[ct][r] + b1[hc * 128 + ct * 16 + l16];
        v = 0.5f * v * (1.f + erff(v * 0.70710678118654752f));
        int rit = quad * 4 + r;
        int col = ct * 16 + l16;
        int ck = col >> 3;
        sH[wv][rit * 128 + (((ck ^ rit) & 15) << 3) + (col & 7)] = f2bf(v);
      }
    __syncthreads();   // H visible
#pragma unroll
    for (int kc = 0; kc < 4; ++kc) {
      int ck = kc * 4 + quad;
      short8 hf = *(const short8*)&sH[wv][l16 * 128 + (((ck ^ l16) & 15) << 3)];
      int kg = hc * 4 + kc;
#pragma unroll
      for (int ct = 0; ct < 8; ++ct) {
        int n = ct * 16 + l16;
        short8 bf = *(const short8*)&W2p[(((size_t)kg * 4 + quad) * 128 + n) << 3];
        oacc[ct] = __builtin_amdgcn_mfma_f32_16x16x32_bf16(hf, bf, oacc[ct], 0, 0, 0);
      }
    }
  }
#pragma unroll
  for (int ct = 0; ct < 8; ++ct)
#pragma unroll
    for (int r = 0; r < 4; ++r) {
      int row = bm + wv * 16 + quad * 4 + r;
      int col = ct * 16 + l16;
      out[(size_t)row * 128 + col] += oacc[ct][r] + b2[col];
    }
}

// ---------------------------------------------------------------------------
// LayerNorm kernels (dim 128 / dim 64), one thread per row
// ---------------------------------------------------------------------------
__global__ __launch_bounds__(256) void k_ln128(const float* __restrict__ in, const float* __restrict__ g,
    const float* __restrict__ bb, float* __restrict__ out, int rows) {
  int t = blockIdx.x * 256 + threadIdx.x;
  if (t >= rows) return;
  const float4* row = (const float4*)(in + (size_t)t * 128);
  float4 v[32];
  float s = 0.f, ss = 0.f;
#pragma unroll
  for (int i = 0; i < 32; ++i) {
    float4 r = row[i]; v[i] = r;
    s += r.x + r.y + r.z + r.w;
    ss += r.x*r.x + r.y*r.y + r.z*r.z + r.w*r.w;
  }
  float m = s * (1.f/128.f);
  float var = ss * (1.f/128.f) - m*m;
  float rs = rsqrtf(var + LN_EPS);
  float4* orow = (float4*)(out + (size_t)t * 128);
#pragma unroll
  for (int i = 0; i < 32; ++i) {
    float4 r = v[i];
    float4 o;
    o.x = (r.x - m) * rs * g[4*i+0] + bb[4*i+0];
    o.y = (r.y - m) * rs * g[4*i+1] + bb[4*i+1];
    o.z = (r.z - m) * rs * g[4*i+2] + bb[4*i+2];
    o.w = (r.w - m) * rs * g[4*i+3] + bb[4*i+3];
    orow[i] = o;
  }
}

__global__ __launch_bounds__(256) void k_ln64(const float* __restrict__ in, const float* __restrict__ g,
    const float* __restrict__ bb, float* __restrict__ out, int rows) {
  int t = blockIdx.x * 256 + threadIdx.x;
  if (t >= rows) return;
  const float4* row = (const float4*)(in + (size_t)t * 64);
  float v[64];
  float s = 0.f, ss = 0.f;
#pragma unroll
  for (int i = 0; i < 16; ++i) {
    float4 r = row[i];
    v[4*i] = r.x; v[4*i+1] = r.y; v[4*i+2] = r.z; v[4*i+3] = r.w;
    s += r.x + r.y + r.z + r.w;
    ss += r.x*r.x + r.y*r.y + r.z*r.z + r.w*r.w;
  }
  float m = s * (1.f/64.f);
  float var = ss * (1.f/64.f) - m*m;
  float rs = rsqrtf(var + LN_EPS);
#pragma unroll
  for (int i = 0; i < 64; ++i)
    out[(size_t)t * 64 + i] = (v[i] - m) * rs * g[i] + bb[i];
}

// ---------------------------------------------------------------------------
// K7: MFMA attention, unchanged.
// ---------------------------------------------------------------------------
__global__ __launch_bounds__(256) void k_attn(const float* __restrict__ q,
    const float* __restrict__ kg, const float* __restrict__ vg, float* __restrict__ o) {
  __shared__ __align__(16) unsigned short ldsKP[14848];
  __shared__ __align__(16) unsigned short ldsV[16128];
  int blk = blockIdx.x;
  int chunk = blk % 14;
  int bh = blk / 14;
  int h = bh & 1, b = bh >> 1;
  int tid = threadIdx.x;
  int wv = tid >> 6, lane = tid & 63;
  int quad = lane >> 4, l16 = lane & 15;

  const float* kb = kg + (size_t)b * NS * 128 + h * 64;
  const float* vb = vg + (size_t)b * NS * 128 + h * 64;

  for (int t = tid; t < KPAD * 8; t += 256) {
    int key = t >> 3, ck = t & 7;
    short8 pk, pv;
    if (key < NS) {
      const float* ksrc = kb + (size_t)key * 128 + ck * 8;
      const float* vsrc = vb + (size_t)key * 128 + ck * 8;
      float4 a = *(const float4*)ksrc;
      float4 c = *(const float4*)(ksrc + 4);
      pk[0]=(short)f2bf(a.x); pk[1]=(short)f2bf(a.y); pk[2]=(short)f2bf(a.z); pk[3]=(short)f2bf(a.w);
      pk[4]=(short)f2bf(c.x); pk[5]=(short)f2bf(c.y); pk[6]=(short)f2bf(c.z); pk[7]=(short)f2bf(c.w);
      float4 e = *(const float4*)vsrc;
      float4 g = *(const float4*)(vsrc + 4);
      pv[0]=(short)f2bf(e.x); pv[1]=(short)f2bf(e.y); pv[2]=(short)f2bf(e.z); pv[3]=(short)f2bf(e.w);
      pv[4]=(short)f2bf(g.x); pv[5]=(short)f2bf(g.y); pv[6]=(short)f2bf(g.z); pv[7]=(short)f2bf(g.w);
    } else {
      pk = (short8)0; pv = (short8)0;
    }
    *(short8*)&ldsKP[key * 64 + ((ck ^ (key & 7)) << 3)] = pk;
    *(short8*)&ldsV[key * 72 + ck * 8] = pv;
  }

  int qrow = chunk * 64 + wv * 16 + l16;
  int qrowc = qrow < ND ? qrow : ND - 1;
  const float* qsrc = q + ((size_t)b * ND + qrowc) * 128 + h * 64 + quad * 8;
  short8 aq0, aq1;
  {
    float4 a = *(const float4*)qsrc;
    float4 c = *(const float4*)(qsrc + 4);
    aq0[0]=(short)f2bf(a.x); aq0[1]=(short)f2bf(a.y); aq0[2]=(short)f2bf(a.z); aq0[3]=(short)f2bf(a.w);
    aq0[4]=(short)f2bf(c.x); aq0[5]=(short)f2bf(c.y); aq0[6]=(short)f2bf(c.z); aq0[7]=(short)f2bf(c.w);
    float4 e = *(const float4*)(qsrc + 32);
    float4 g = *(const float4*)(qsrc + 36);
    aq1[0]=(short)f2bf(e.x); aq1[1]=(short)f2bf(e.y); aq1[2]=(short)f2bf(e.z); aq1[3]=(short)f2bf(e.w);
    aq1[4]=(short)f2bf(g.x); aq1[5]=(short)f2bf(g.y); aq1[6]=(short)f2bf(g.z); aq1[7]=(short)f2bf(g.w);
  }
  __syncthreads();

  f32x4 acc[14];
#pragma unroll
  for (int ct = 0; ct < 14; ++ct) {
    int key = ct * 16 + l16;
    short8 bk0 = *(const short8*)&ldsKP[key * 64 + ((quad ^ (key & 7)) << 3)];
    short8 bk1 = *(const short8*)&ldsKP[key * 64 + (((4 + quad) ^ (key & 7)) << 3)];
    f32x4 z = {0.f, 0.f, 0.f, 0.f};
    z = __builtin_amdgcn_mfma_f32_16x16x32_bf16(aq0, bk0, z, 0, 0, 0);
    z = __builtin_amdgcn_mfma_f32_16x16x32_bf16(aq1, bk1, z, 0, 0, 0);
    acc[ct] = z;
  }

  const float scale = 0.17677669529663687f;  // 32^-0.5
  float rmax[4] = {-1e30f, -1e30f, -1e30f, -1e30f};
#pragma unroll
  for (int ct = 0; ct < 14; ++ct) {
    bool msk = (ct * 16 + l16) >= NS;
#pragma unroll
    for (int r = 0; r < 4; ++r) {
      float sv = msk ? -1e30f : acc[ct][r] * scale;
      acc[ct][r] = sv;
      rmax[r] = fmaxf(rmax[r], sv);
    }
  }
#pragma unroll
  for (int m = 1; m < 16; m <<= 1)
#pragma unroll
    for (int r = 0; r < 4; ++r) rmax[r] = fmaxf(rmax[r], __shfl_xor(rmax[r], m));
  float rsum[4] = {0.f, 0.f, 0.f, 0.f};
#pragma unroll
  for (int ct = 0; ct < 14; ++ct)
#pragma unroll
    for (int r = 0; r < 4; ++r) {
      float e = __expf(acc[ct][r] - rmax[r]);
      acc[ct][r] = e;
      rsum[r] += e;
    }
#pragma unroll
  for (int m = 1; m < 16; m <<= 1)
#pragma unroll
    for (int r = 0; r < 4; ++r) rsum[r] += __shfl_xor(rsum[r], m);
  float rinv[4];
#pragma unroll
  for (int r = 0; r < 4; ++r) rinv[r] = 1.f / rsum[r];

  __syncthreads();

#pragma unroll
  for (int ct = 0; ct < 14; ++ct)
#pragma unroll
    for (int r = 0; r < 4; ++r) {
      int prow = wv * 16 + quad * 4 + r;
      ldsKP[prow * 232 + ct * 16 + l16] = f2bf(acc[ct][r] * rinv[r]);
    }
  __syncthreads();

  f32x4 oacc[4];
#pragma unroll
  for (int ot = 0; ot < 4; ++ot) oacc[ot] = (f32x4){0.f, 0.f, 0.f, 0.f};
#pragma unroll
  for (int kc = 0; kc < 7; ++kc) {
    short8 ap = *(const short8*)&ldsKP[(wv * 16 + l16) * 232 + kc * 32 + quad * 8];
    int keybase = kc * 32 + quad * 8;
#pragma unroll
    for (int ot = 0; ot < 4; ++ot) {
      int dcol = ot * 16 + l16;
      short8 bv;
#pragma unroll
      for (int j = 0; j < 8; ++j) bv[j] = (short)ldsV[(keybase + j) * 72 + dcol];
      oacc[ot] = __builtin_amdgcn_mfma_f32_16x16x32_bf16(ap, bv, oacc[ot], 0, 0, 0);
    }
  }

#pragma unroll
  for (int ot = 0; ot < 4; ++ot)
#pragma unroll
    for (int r = 0; r < 4; ++r) {
      int rowg = chunk * 64 + wv * 16 + quad * 4 + r;
      if (rowg < ND)
        o[((size_t)b * ND + rowg) * 128 + h * 64 + ot * 16 + l16] = oacc[ot][r];
    }
}

// ---------------------------------------------------------------------------
// K8: bilinear grid-sample of pos_embed at pos_down, accumulate into out
// ---------------------------------------------------------------------------
__global__ __launch_bounds__(256) void k_posfeat(const float* __restrict__ pd,
    const float* __restrict__ pe, float* __restrict__ out) {
  int t = blockIdx.x * 256 + threadIdx.x;
  int row = t >> 5, lane = t & 31;
  if (row >= B_ * ND) return;
  float gx = pd[(size_t)2*row] * 2.f - 1.f;
  float gy = pd[(size_t)2*row+1] * 2.f - 1.f;
  float ix = ((gx + 1.f) * 56.f - 1.f) * 0.5f;
  float iy = ((gy + 1.f) * 56.f - 1.f) * 0.5f;
  float x0 = floorf(ix), y0 = floorf(iy);
  float wx1 = ix - x0, wy1 = iy - y0;
  float wx0 = 1.f - wx1, wy0 = 1.f - wy1;
  float4 acc = make_float4(0.f, 0.f, 0.f, 0.f);
#pragma unroll
  for (int cy = 0; cy < 2; ++cy) {
#pragma unroll
    for (int cx = 0; cx < 2; ++cx) {
      float xc = x0 + (float)cx, yc = y0 + (float)cy;
      float wgt = (cx ? wx1 : wx0) * (cy ? wy1 : wy0);
      bool valid = (xc >= 0.f) && (xc < 56.f) && (yc >= 0.f) && (yc < 56.f);
      if (valid) {
        int lin = (int)yc * 56 + (int)xc;
        float4 pv = ((const float4*)(pe + (size_t)lin * 128))[lane];
        acc.x += wgt * pv.x; acc.y += wgt * pv.y;
        acc.z += wgt * pv.z; acc.w += wgt * pv.w;
      }
    }
  }
  float4* op = (float4*)(out + (size_t)row * 128) + lane;
  float4 cur = *op;
  cur.x += acc.x; cur.y += acc.y; cur.z += acc.z; cur.w += acc.w;
  *op = cur;
}

// ---------------------------------------------------------------------------
// launcher
// ---------------------------------------------------------------------------
extern "C" void kernel_launch(void* const* d_in, const int* in_sizes, int n_in,
                              void* d_out, int out_size, void* d_ws, size_t ws_size,
                              hipStream_t stream) {
  const float* x      = (const float*)d_in[0];
  const float* pos    = (const float*)d_in[1];
  const float* pe     = (const float*)d_in[2];
  const float* nu     = (const float*)d_in[3];
  const float* norm_g = (const float*)d_in[4];
  const float* norm_b = (const float*)d_in[5];
  const float* conf_w = (const float*)d_in[6];
  const float* conf_b = (const float*)d_in[7];
  const float* n1g    = (const float*)d_in[8];
  const float* n1b    = (const float*)d_in[9];
  const float* q_w    = (const float*)d_in[10];
  const float* k_w    = (const float*)d_in[11];
  const float* v_w    = (const float*)d_in[12];
  const float* proj_w = (const float*)d_in[13];
  const float* proj_b = (const float*)d_in[14];
  const float* sr_w   = (const float*)d_in[15];
  const float* sr_b   = (const float*)d_in[16];
  const float* srn_g  = (const float*)d_in[17];
  const float* srn_b  = (const float*)d_in[18];
  const float* fc_w   = (const float*)d_in[19];
  const float* fc_b   = (const float*)d_in[20];
  const float* n2g    = (const float*)d_in[21];
  const float* n2b    = (const float*)d_in[22];
  const float* fc1_w  = (const float*)d_in[23];
  const float* fc1_b  = (const float*)d_in[24];
  const float* fc2_w  = (const float*)d_in[25];
  const float* fc2_b  = (const float*)d_in[26];

  char* ws = (char*)d_ws;
  // workspace layout (bytes); total 190,578,688 (unchanged)
  double*         scores = (double*)(ws + 0);                //  1,580,544
  int*            idx    = (int*)(ws + 1605632);             //    200,704
  float*          xd     = (float*)(ws + 1835008);           // 13,647,872
  float*          xn     = (float*)(ws + 15728640);          // 13,647,872
  float*          pd     = (float*)(ws + 29491200);          //    426,496
  float*          qb     = (float*)(ws + 30408704);          // 27,295,744; T alias; later q/O2
  float*          ob     = (float*)(ws + 58720256);          // 27,295,744; T tail alias; later xn2
  float*          wt     = (float*)(ws + 86507520);          //    262,144
  unsigned short* W1p    = (unsigned short*)(ws + 86769664); //    131,072
  unsigned short* W2p    = (unsigned short*)(ws + 86900736); //    131,072 (ends 87,031,808)
  char*           big    = ws + 87031808;                    // 103,546,880 region
  float*          S      = (float*)big;                      // 52,183,040 (dead after coef+transpose)
  float*          T      = qb;                               // 51,380,224 channel-major planes (dead after filter2)
  float*          Kc     = (float*)(big + 52183040);         //  7,225,344 coefficient planes (dead after filter2)
  float*          P      = (float*)big;                      // 51,380,224 (reuses dead S; dead after conv)
  float*          xs_c   = (float*)(big + 59408384);         //  3,211,264
  float*          xs_n   = (float*)(big + 62619648);         //  3,211,264
  float*          kbuf   = (float*)(big + 65830912);         //  6,422,528
  float*          vbuf   = (float*)(big + 72253440);         //  6,422,528 (ends 78,675,968 < 103,546,880)
  float*          O2     = qb;
  float*          xn2    = ob;
  float*          out    = (float*)d_out;

  // 1) f64 conf+gumbel scores
  k_conf<<<(B_ * N_) / 256, 256, 0, stream>>>(x, norm_g, norm_b, conf_w, conf_b, nu, scores);
  // 2) top-784 per batch (rank-by-count, f64 keys)
  k_rank<<<B_ * NCHUNK, 256, 0, stream>>>(scores, idx);
  // 3) gather + LN(norm1)
  k_gather_ln<<<(B_ * ND + 255) / 256, 256, 0, stream>>>(x, pos, idx, n1g, n1b, xd, xn, pd);
  // 4) token2map scatter (wave-per-token, coalesced atomics, f64 binning)
  hipMemsetAsync(S, 0, (size_t)B_ * HW * 65 * sizeof(float), stream);
  k_scatter<<<(B_ * N_ * 64) / 256, 256, 0, stream>>>(x, n1g, n1b, pos, S);
  // 5) gaussian reconstruct, 3 passes
  k_coef<<<BHW / 256, 256, 0, stream>>>(S, Kc);
  k_transpose<<<BHW / 64, 256, 0, stream>>>(S, T);
  k_filter2<<<B_ * 64, 256, 0, stream>>>(T, Kc, P);
  // 6) conv weights transpose + MLP weight pack; conv-as-GEMM; srnorm
  k_wt<<<(1024 * 64) / 256, 256, 0, stream>>>(sr_w, wt);
  k_wpack<<<65536 / 256, 256, 0, stream>>>(fc1_w, fc2_w, W1p, W2p);
  dim3 g_conv(NS * B_ / 64, 1);
  k_gemm<<<g_conv, 256, 0, stream>>>(P, wt, sr_b, nullptr, xs_c, B_ * NS, 64, 1024);
  k_ln64<<<(B_ * NS + 255) / 256, 256, 0, stream>>>(xs_c, srn_g, srn_b, xs_n, B_ * NS);
  // 7) k, v, q projections (q GEMM overwrites T region -- T is dead by now)
  dim3 g_kv(B_ * NS / 64, 2);
  k_gemm<<<g_kv, 256, 0, stream>>>(xs_n, k_w, nullptr, nullptr, kbuf, B_ * NS, 128, 64);
  k_gemm<<<g_kv, 256, 0, stream>>>(xs_n, v_w, nullptr, nullptr, vbuf, B_ * NS, 128, 64);
  dim3 g_row(B_ * ND / 64, 2);
  k_gemm<<<g_row, 256, 0, stream>>>(xn, q_w, nullptr, nullptr, qb, B_ * ND, 128, 64);
  // 8) attention (MFMA bf16)
  k_attn<<<B_ * 2 * 14, 256, 0, stream>>>(qb, kbuf, vbuf, ob);
  // 9) x2 = x_down@fc_w + fc_b + (o@proj_w + proj_b)  -> d_out
  k_gemm<<<g_row, 256, 0, stream>>>(ob, proj_w, proj_b, nullptr, O2, B_ * ND, 128, 128);
  k_gemm<<<g_row, 256, 0, stream>>>(xd, fc_w, fc_b, O2, out, B_ * ND, 128, 64);
  // 10) MLP: LN128 then MFMA fused fc1+gelu+fc2 (accumulates into out)
  k_ln128<<<(B_ * ND + 255) / 256, 256, 0, stream>>>(out, n2g, n2b, xn2, B_ * ND);
  k_mlp<<<B_ * ND / 64, 256, 0, stream>>>(xn2, W1p, fc1_b, W2p, fc2_b, out);
  // 11) + pos_feat (bilinear grid sample)
  k_posfeat<<<(B_ * ND * 32) / 256, 256, 0, stream>>>(pd, pe, out);
}

// Round 3
// 819.765 us; speedup vs baseline: 1.0964x; 1.0964x over previous
//
#include <hip/hip_runtime.h>
#include <math.h>

#define DEVINL __device__ __forceinline__

constexpr int B_ = 64;
constexpr int N_ = 3136;
constexpr int C_ = 64;        // DIM
constexpr int NG = 49;        // N_grid
constexpr int NSAMP = 784;    // SAMPLE_NUM
constexpr int ND = NG + NSAMP;     // 833
constexpr int NREST = N_ - NG;     // 3087
constexpr int H_ = 56, W_ = 56;
constexpr int HW = H_ * W_;        // 3136
constexpr int BHW = B_ * HW;       // 200704
constexpr int NS = 14 * 14;        // 196 kv tokens
constexpr int KPAD = 224;          // 196 padded to 7*32
constexpr float LN_EPS = 1e-5f;
constexpr float EPS6 = 1e-6f;

typedef __attribute__((ext_vector_type(8))) short short8;
typedef __attribute__((ext_vector_type(4))) float f32x4;

DEVINL unsigned short f2bf(float f) {
  unsigned int u = __float_as_uint(f);
  unsigned int r = u + 0x7FFFu + ((u >> 16) & 1u);
  return (unsigned short)(r >> 16);
}

DEVINL unsigned long long mapkey(double d) {
  long long bits = __double_as_longlong(d);
  unsigned long long ub = (unsigned long long)bits;
  return (bits < 0) ? ~ub : (ub | 0x8000000000000000ULL);   // monotone map
}

// ---------------------------------------------------------------------------
// K1: conf scores in FP64 (discrete top-k decision must match f64 np ref)
// ---------------------------------------------------------------------------
__global__ __launch_bounds__(256) void k_conf(
    const float* __restrict__ x, const float* __restrict__ ng, const float* __restrict__ nb,
    const float* __restrict__ cw, const float* __restrict__ cb,
    const float* __restrict__ nu, double* __restrict__ scores) {
  int t = blockIdx.x * 256 + threadIdx.x;
  if (t >= B_ * N_) return;
  int b = t / N_, n = t - b * N_;
  if (n < NG) return;
  const float4* row = (const float4*)(x + (size_t)t * C_);
  float v[C_];
#pragma unroll
  for (int i = 0; i < 16; ++i) {
    float4 r = row[i];
    v[4*i] = r.x; v[4*i+1] = r.y; v[4*i+2] = r.z; v[4*i+3] = r.w;
  }
  double sd = 0.0;
#pragma unroll
  for (int i = 0; i < C_; ++i) sd += (double)v[i];
  double md = sd * (1.0/64.0);
  double vd = 0.0;
#pragma unroll
  for (int i = 0; i < C_; ++i) { double d = (double)v[i] - md; vd += d * d; }
  vd *= (1.0/64.0);
  double rsd = 1.0 / sqrt(vd + 1e-5);
  double conf = (double)cb[0];
#pragma unroll
  for (int i = 0; i < C_; ++i) {
    double xnv = ((double)v[i] - md) * rsd;
    conf += (xnv * (double)ng[i] + (double)nb[i]) * (double)cw[i];
  }
  double u = (double)nu[(size_t)b * NREST + (n - NG)];
  double noise = -log(-log(u + 1e-6) + 1e-6);
  scores[(size_t)b * NREST + (n - NG)] = conf + noise;
}

// ---------------------------------------------------------------------------
// K2 (ROUND-9): rank-by-count, 2-D split. Block = (batch, e-chunk 512,
// j-chunk 1029). 1344 blocks (~21 waves/CU) vs round-8's 448 (~6/CU) --
// enough TLP to hide LDS broadcast latency. Partial counts atomicAdd into
// counts[b][e]; predicate partitions exactly over j so sums are exact.
// ---------------------------------------------------------------------------
constexpr int JCH = 1029;            // 3 * 1029 = 3087 exactly
constexpr int NJC = 3;
constexpr int ECH = 512;
constexpr int NEC = 7;               // 7 * 512 = 3584 >= 3087

__global__ __launch_bounds__(256) void k_rank(const double* __restrict__ scores,
                                              int* __restrict__ counts) {
  __shared__ unsigned long long ls[JCH];   // 8232 B
  int blk = blockIdx.x;
  int b = blk / (NEC * NJC);
  int r = blk - b * (NEC * NJC);
  int ec = r / NJC, jc = r - ec * NJC;
  const double* sc = scores + (size_t)b * NREST;
  int j0 = jc * JCH;
  for (int i = threadIdx.x; i < JCH; i += 256)
    ls[i] = mapkey(sc[j0 + i]);
  __syncthreads();
  int e0 = ec * ECH + threadIdx.x;
  int e1 = e0 + 256;
  unsigned long long k0 = (e0 < NREST) ? mapkey(sc[e0]) : 0ULL;
  unsigned long long k1 = (e1 < NREST) ? mapkey(sc[e1]) : 0ULL;
  int c0 = 0, c1 = 0;
#pragma unroll 4
  for (int jj = 0; jj < JCH; ++jj) {
    unsigned long long kj = ls[jj];
    int j = j0 + jj;
    c0 += (int)((kj > k0) | ((kj == k0) & (j < e0)));
    c1 += (int)((kj > k1) | ((kj == k1) & (j < e1)));
  }
  if (e0 < NREST) atomicAdd(&counts[(size_t)b * NREST + e0], c0);
  if (e1 < NREST) atomicAdd(&counts[(size_t)b * NREST + e1], c1);
}

// ---------------------------------------------------------------------------
// K2b: write idx[rank]=e for rank < 784. Ranks are a permutation of
// 0..3086 under (desc key, asc idx) total order -> output is exactly
// jax.lax.top_k order.
// ---------------------------------------------------------------------------
__global__ __launch_bounds__(256) void k_rankw(const int* __restrict__ counts,
                                               int* __restrict__ idx) {
  int t = blockIdx.x * 256 + threadIdx.x;
  if (t >= B_ * NREST) return;
  int b = t / NREST, e = t - b * NREST;
  int c = counts[t];
  if (c < NSAMP) idx[(size_t)b * NSAMP + c] = e;
}

// ---------------------------------------------------------------------------
// K3: gather x_down/pos_down rows; LayerNorm(x_down, norm1) -> xn
// ---------------------------------------------------------------------------
__global__ __launch_bounds__(256) void k_gather_ln(
    const float* __restrict__ x, const float* __restrict__ pos, const int* __restrict__ idx,
    const float* __restrict__ n1g, const float* __restrict__ n1b,
    float* __restrict__ xd, float* __restrict__ xn, float* __restrict__ pd) {
  int t = blockIdx.x * 256 + threadIdx.x;
  if (t >= B_ * ND) return;
  int b = t / ND, r = t - b * ND;
  int srcn = (r < NG) ? r : (NG + idx[(size_t)b * NSAMP + (r - NG)]);
  const float4* row = (const float4*)(x + ((size_t)b * N_ + srcn) * C_);
  float4* xdr = (float4*)(xd + (size_t)t * C_);
  float v[C_];
  float s = 0.f, ss = 0.f;
#pragma unroll
  for (int i = 0; i < 16; ++i) {
    float4 rr = row[i];
    xdr[i] = rr;
    v[4*i] = rr.x; v[4*i+1] = rr.y; v[4*i+2] = rr.z; v[4*i+3] = rr.w;
    s += rr.x + rr.y + rr.z + rr.w;
    ss += rr.x*rr.x + rr.y*rr.y + rr.z*rr.z + rr.w*rr.w;
  }
  float m = s * (1.f/64.f);
  float var = ss * (1.f/64.f) - m*m;
  float rs = rsqrtf(var + LN_EPS);
#pragma unroll
  for (int i = 0; i < C_; ++i)
    xn[(size_t)t * C_ + i] = (v[i] - m) * rs * n1g[i] + n1b[i];
  pd[(size_t)2*t]   = pos[((size_t)b * N_ + srcn) * 2];
  pd[(size_t)2*t+1] = pos[((size_t)b * N_ + srcn) * 2 + 1];
}

// ---------------------------------------------------------------------------
// K4: scatter: one WAVE per token, lane = channel; coalesced atomics.
// ---------------------------------------------------------------------------
__global__ __launch_bounds__(256) void k_scatter(
    const float* __restrict__ x, const float* __restrict__ n1g, const float* __restrict__ n1b,
    const float* __restrict__ pos, float* __restrict__ S) {
  int gt = blockIdx.x * 256 + threadIdx.x;
  int tok = gt >> 6, lane = gt & 63;
  if (tok >= B_ * N_) return;
  int b = tok / N_;
  float v = x[(size_t)tok * C_ + lane];
  float s = v, ss = v * v;
#pragma unroll
  for (int m = 32; m > 0; m >>= 1) {
    s += __shfl_xor(s, m);
    ss += __shfl_xor(ss, m);
  }
  float mean = s * (1.f/64.f);
  float var = ss * (1.f/64.f) - mean * mean;
  float rs = rsqrtf(var + LN_EPS);
  double px = fmin(fmax((double)pos[(size_t)2*tok],   0.0), 1.0) * (double)(W_ - 1);
  double py = fmin(fmax((double)pos[(size_t)2*tok+1], 0.0), 1.0) * (double)(H_ - 1);
  int xi = (int)rint(px), yi = (int)rint(py);
  float* base = S + ((size_t)b * HW + yi * W_ + xi) * 65;
  atomicAdd(base + lane, (v - mean) * rs * n1g[lane] + n1b[lane]);
  if (lane == 0) atomicAdd(base + 64, 1.f);
}

// ---------------------------------------------------------------------------
// K5a: per-pixel 3x3 coefficient planes from the mask channel.
// ---------------------------------------------------------------------------
__global__ __launch_bounds__(256) void k_coef(const float* __restrict__ S, float* __restrict__ Kc) {
  int t = blockIdx.x * 256 + threadIdx.x;
  if (t >= BHW) return;
  int b = t / HW, p = t - b * HW;
  int y = p / W_, x = p - y * W_;
  const float* Sb = S + (size_t)b * HW * 65;
  const float e1 = 0.882496902584595f;   // exp(-1/8)
  const float e2 = 0.778800783071405f;   // exp(-1/4)
  const float Z = 1.f + 4.f * (e1 + e2);
  float m0 = Sb[(size_t)p * 65 + 64];
  float mb0 = m0 > 0.f ? 1.f : 0.f;
  float cfac = mb0 / (m0 + EPS6);
  float sc[9];
  float mi = 0.f;
  int q = 0;
#pragma unroll
  for (int dy = -1; dy <= 1; ++dy) {
#pragma unroll
    for (int dx = -1; dx <= 1; ++dx) {
      int ny = y + dy, nx = x + dx;
      bool in = (ny >= 0 && ny < H_ && nx >= 0 && nx < W_);
      float w = ((dx == 0 && dy == 0) ? 1.f : ((dx*dx + dy*dy) == 1 ? e1 : e2)) / Z;
      float mm = in ? Sb[(size_t)(ny * W_ + nx) * 65 + 64] : 0.f;
      float mb = mm > 0.f ? 1.f : 0.f;
      mi += w * mb;
      sc[q] = in ? (w * mb / (mm + EPS6)) : 0.f;
      ++q;
    }
  }
  float outer = (1.f - mb0) * ((mi > 0.f ? 1.f : 0.f) / (mi + EPS6));
#pragma unroll
  for (int qq = 0; qq < 9; ++qq) {
    float cq = outer * sc[qq];
    if (qq == 4) cq += cfac;
    Kc[(size_t)qq * BHW + t] = cq;
  }
}

// ---------------------------------------------------------------------------
// K5b: transpose S[p][65] -> channel-major planes T[b][c][HW].
// ---------------------------------------------------------------------------
__global__ __launch_bounds__(256) void k_transpose(const float* __restrict__ S, float* __restrict__ T) {
  __shared__ float ls[64 * 65];
  int g0 = blockIdx.x * 64;            // global pixel base (batch-major)
  int b = g0 / HW, p0 = g0 - b * HW;
  const float4* src = (const float4*)(S + (size_t)g0 * 65);
  for (int i = threadIdx.x; i < (64 * 65) / 4; i += 256)
    *(float4*)&ls[i * 4] = src[i];
  __syncthreads();
  for (int i = threadIdx.x; i < 64 * 64; i += 256) {
    int c = i >> 6, px = i & 63;
    T[((size_t)(b * 64 + c)) * HW + p0 + px] = ls[px * 65 + c];
  }
}

// ---------------------------------------------------------------------------
// K5c: spatially-varying 3x3 conv on channel planes -> conv-patch layout P.
// ---------------------------------------------------------------------------
__global__ __launch_bounds__(256) void k_filter2(
    const float* __restrict__ T, const float* __restrict__ Kc, float* __restrict__ P) {
  int plane = blockIdx.x;              // b*64 + c
  int b = plane >> 6, c = plane & 63;
  int tid = threadIdx.x;
  const float* Tp = T + (size_t)plane * HW;
  const float* Kb = Kc + (size_t)b * HW;
  for (int p0 = 0; p0 < HW; p0 += 256) {
    int p = p0 + tid;
    if (p < HW) {
      int y = p / W_, x = p - y * W_;
      float acc = 0.f;
      int q = 0;
#pragma unroll
      for (int dy = -1; dy <= 1; ++dy) {
#pragma unroll
        for (int dx = -1; dx <= 1; ++dx) {
          int ny = y + dy; ny = ny < 0 ? 0 : (ny > H_ - 1 ? H_ - 1 : ny);
          int nx = x + dx; nx = nx < 0 ? 0 : (nx > W_ - 1 ? W_ - 1 : nx);
          acc += Kb[(size_t)q * BHW + p] * Tp[ny * W_ + nx];
          ++q;
        }
      }
      int j = (y >> 2) * 14 + (x >> 2);
      int colb = ((y & 3) << 2) + (x & 3);
      P[((size_t)(b * NS + j)) * 1024 + c * 16 + colb] = acc;
    }
  }
}

// ---------------------------------------------------------------------------
// K6: transpose sr_w (co,ci,ky,kx) -> w_t[kk=ci*16+ky*4+kx][co]
// ---------------------------------------------------------------------------
__global__ __launch_bounds__(256) void k_wt(const float* __restrict__ srw, float* __restrict__ wt) {
  int t = blockIdx.x * 256 + threadIdx.x;
  if (t >= 1024 * 64) return;
  int kk = t >> 6, co = t & 63;
  int ci = kk >> 4, r = kk & 15;
  wt[t] = srw[(((size_t)co * 64 + ci) << 4) + r];
}

// ---------------------------------------------------------------------------
// K6b: pack fc1/fc2 weights into B-frag-contiguous bf16 layout
// ---------------------------------------------------------------------------
__global__ __launch_bounds__(256) void k_wpack(const float* __restrict__ W1, const float* __restrict__ W2,
    unsigned short* __restrict__ W1p, unsigned short* __restrict__ W2p) {
  int t = blockIdx.x * 256 + threadIdx.x;
  if (t >= 65536) return;
  {
    int j = t & 7;
    int n = (t >> 3) & 511;
    int qk = t >> 12;            // 0..15
    int quad = qk & 3, kc = qk >> 2;
    int k = kc * 32 + quad * 8 + j;
    W1p[t] = f2bf(W1[(size_t)k * 512 + n]);
  }
  {
    int j = t & 7;
    int n = (t >> 3) & 127;
    int qk = t >> 10;            // 0..63
    int quad = qk & 3, kg = qk >> 2;
    int k = kg * 32 + quad * 8 + j;
    W2p[t] = f2bf(W2[(size_t)k * 128 + n]);
  }
}

// ---------------------------------------------------------------------------
// Tiled fp32 GEMM: C[M,N] = A[M,K] @ B[K,N] (+bias)(+add)
// ---------------------------------------------------------------------------
__global__ __launch_bounds__(256) void k_gemm(
    const float* __restrict__ A, const float* __restrict__ Bw,
    const float* __restrict__ bias, const float* __restrict__ add,
    float* __restrict__ Cout, int M, int N, int K) {
  __shared__ float sA[16][68];
  __shared__ float sB[16][64];
  int bm = blockIdx.x * 64, bn = blockIdx.y * 64;
  int tid = threadIdx.x;
  int tx = tid & 15, ty = tid >> 4;
  float acc[4][4] = {{0.f}};
  for (int k0 = 0; k0 < K; k0 += 16) {
    int e = tid << 2;
    int am = e >> 4, ak = e & 15;
    float4 a4 = *(const float4*)(A + (size_t)(bm + am) * K + k0 + ak);
    sA[ak + 0][am] = a4.x; sA[ak + 1][am] = a4.y; sA[ak + 2][am] = a4.z; sA[ak + 3][am] = a4.w;
    int bk = e >> 6, nn = e & 63;
    float4 b4 = *(const float4*)(Bw + (size_t)(k0 + bk) * N + bn + nn);
    *(float4*)&sB[bk][nn] = b4;
    __syncthreads();
#pragma unroll
    for (int kk = 0; kk < 16; ++kk) {
      float a[4], bb[4];
#pragma unroll
      for (int i = 0; i < 4; ++i) a[i] = sA[kk][ty * 4 + i];
#pragma unroll
      for (int i = 0; i < 4; ++i) bb[i] = sB[kk][tx * 4 + i];
#pragma unroll
      for (int i = 0; i < 4; ++i)
#pragma unroll
        for (int jj = 0; jj < 4; ++jj) acc[i][jj] += a[i] * bb[jj];
    }
    __syncthreads();
  }
#pragma unroll
  for (int i = 0; i < 4; ++i) {
    int row = bm + ty * 4 + i;
#pragma unroll
    for (int jj = 0; jj < 4; ++jj) {
      int col = bn + tx * 4 + jj;
      float v = acc[i][jj];
      if (bias) v += bias[col];
      if (add) v += add[(size_t)row * N + col];
      Cout[(size_t)row * N + col] = v;
    }
  }
}

// ---------------------------------------------------------------------------
// K-MLP: MFMA bf16. out += gelu(A@W1+b1)@W2+b2.
// ---------------------------------------------------------------------------
__global__ __launch_bounds__(256) void k_mlp(
    const float* __restrict__ A, const unsigned short* __restrict__ W1p, const float* __restrict__ b1,
    const unsigned short* __restrict__ W2p, const float* __restrict__ b2, float* __restrict__ out) {
  __shared__ __align__(16) unsigned short sA[64 * 128];
  __shared__ __align__(16) unsigned short sH[4][16 * 128];
  int bm = blockIdx.x * 64;
  int tid = threadIdx.x;
  int wv = tid >> 6, lane = tid & 63, quad = lane >> 4, l16 = lane & 15;

  for (int t = tid; t < 64 * 16; t += 256) {
    int row = t >> 4, ck = t & 15;
    const float* src = A + (size_t)(bm + row) * 128 + ck * 8;
    float4 a = *(const float4*)src;
    float4 c = *(const float4*)(src + 4);
    short8 p;
    p[0]=(short)f2bf(a.x); p[1]=(short)f2bf(a.y); p[2]=(short)f2bf(a.z); p[3]=(short)f2bf(a.w);
    p[4]=(short)f2bf(c.x); p[5]=(short)f2bf(c.y); p[6]=(short)f2bf(c.z); p[7]=(short)f2bf(c.w);
    *(short8*)&sA[row * 128 + (((ck ^ row) & 15) << 3)] = p;
  }
  __syncthreads();

  f32x4 oacc[8];
#pragma unroll
  for (int ct = 0; ct < 8; ++ct) oacc[ct] = (f32x4){0.f, 0.f, 0.f, 0.f};

  for (int hc = 0; hc < 4; ++hc) {
    f32x4 acc1[8];
#pragma unroll
    for (int ct = 0; ct < 8; ++ct) acc1[ct] = (f32x4){0.f, 0.f, 0.f, 0.f};
#pragma unroll
    for (int kc = 0; kc < 4; ++kc) {
      int row = wv * 16 + l16;
      int ck = kc * 4 + quad;
      short8 af = *(const short8*)&sA[row * 128 + (((ck ^ row) & 15) << 3)];
#pragma unroll
      for (int ct = 0; ct < 8; ++ct) {
        int n = hc * 128 + ct * 16 + l16;
        short8 bf = *(const short8*)&W1p[(((size_t)kc * 4 + quad) * 512 + n) << 3];
        acc1[ct] = __builtin_amdgcn_mfma_f32_16x16x32_bf16(af, bf, acc1[ct], 0, 0, 0);
      }
    }
    __syncthreads();   // prior GEMM2 reads of sH done (all waves)
#pragma unroll
    for (int ct = 0; ct < 8; ++ct)
#pragma unroll
      for (int r = 0; r < 4; ++r) {
        float v = acc1[ct][r] + b1[hc * 128 + ct * 16 + l16];
        v = 0.5f * v * (1.f + erff(v * 0.70710678118654752f));
        int rit = quad * 4 + r;
        int col = ct * 16 + l16;
        int ck = col >> 3;
        sH[wv][rit * 128 + (((ck ^ rit) & 15) << 3) + (col & 7)] = f2bf(v);
      }
    __syncthreads();   // H visible
#pragma unroll
    for (int kc = 0; kc < 4; ++kc) {
      int ck = kc * 4 + quad;
      short8 hf = *(const short8*)&sH[wv][l16 * 128 + (((ck ^ l16) & 15) << 3)];
      int kg = hc * 4 + kc;
#pragma unroll
      for (int ct = 0; ct < 8; ++ct) {
        int n = ct * 16 + l16;
        short8 bf = *(const short8*)&W2p[(((size_t)kg * 4 + quad) * 128 + n) << 3];
        oacc[ct] = __builtin_amdgcn_mfma_f32_16x16x32_bf16(hf, bf, oacc[ct], 0, 0, 0);
      }
    }
  }
#pragma unroll
  for (int ct = 0; ct < 8; ++ct)
#pragma unroll
    for (int r = 0; r < 4; ++r) {
      int row = bm + wv * 16 + quad * 4 + r;
      int col = ct * 16 + l16;
      out[(size_t)row * 128 + col] += oacc[ct][r] + b2[col];
    }
}

// ---------------------------------------------------------------------------
// LayerNorm kernels (dim 128 / dim 64), one thread per row
// ---------------------------------------------------------------------------
__global__ __launch_bounds__(256) void k_ln128(const float* __restrict__ in, const float* __restrict__ g,
    const float* __restrict__ bb, float* __restrict__ out, int rows) {
  int t = blockIdx.x * 256 + threadIdx.x;
  if (t >= rows) return;
  const float4* row = (const float4*)(in + (size_t)t * 128);
  float4 v[32];
  float s = 0.f, ss = 0.f;
#pragma unroll
  for (int i = 0; i < 32; ++i) {
    float4 r = row[i]; v[i] = r;
    s += r.x + r.y + r.z + r.w;
    ss += r.x*r.x + r.y*r.y + r.z*r.z + r.w*r.w;
  }
  float m = s * (1.f/128.f);
  float var = ss * (1.f/128.f) - m*m;
  float rs = rsqrtf(var + LN_EPS);
  float4* orow = (float4*)(out + (size_t)t * 128);
#pragma unroll
  for (int i = 0; i < 32; ++i) {
    float4 r = v[i];
    float4 o;
    o.x = (r.x - m) * rs * g[4*i+0] + bb[4*i+0];
    o.y = (r.y - m) * rs * g[4*i+1] + bb[4*i+1];
    o.z = (r.z - m) * rs * g[4*i+2] + bb[4*i+2];
    o.w = (r.w - m) * rs * g[4*i+3] + bb[4*i+3];
    orow[i] = o;
  }
}

__global__ __launch_bounds__(256) void k_ln64(const float* __restrict__ in, const float* __restrict__ g,
    const float* __restrict__ bb, float* __restrict__ out, int rows) {
  int t = blockIdx.x * 256 + threadIdx.x;
  if (t >= rows) return;
  const float4* row = (const float4*)(in + (size_t)t * 64);
  float v[64];
  float s = 0.f, ss = 0.f;
#pragma unroll
  for (int i = 0; i < 16; ++i) {
    float4 r = row[i];
    v[4*i] = r.x; v[4*i+1] = r.y; v[4*i+2] = r.z; v[4*i+3] = r.w;
    s += r.x + r.y + r.z + r.w;
    ss += r.x*r.x + r.y*r.y + r.z*r.z + r.w*r.w;
  }
  float m = s * (1.f/64.f);
  float var = ss * (1.f/64.f) - m*m;
  float rs = rsqrtf(var + LN_EPS);
#pragma unroll
  for (int i = 0; i < 64; ++i)
    out[(size_t)t * 64 + i] = (v[i] - m) * rs * g[i] + bb[i];
}

// ---------------------------------------------------------------------------
// K7: MFMA attention, unchanged.
// ---------------------------------------------------------------------------
__global__ __launch_bounds__(256) void k_attn(const float* __restrict__ q,
    const float* __restrict__ kg, const float* __restrict__ vg, float* __restrict__ o) {
  __shared__ __align__(16) unsigned short ldsKP[14848];
  __shared__ __align__(16) unsigned short ldsV[16128];
  int blk = blockIdx.x;
  int chunk = blk % 14;
  int bh = blk / 14;
  int h = bh & 1, b = bh >> 1;
  int tid = threadIdx.x;
  int wv = tid >> 6, lane = tid & 63;
  int quad = lane >> 4, l16 = lane & 15;

  const float* kb = kg + (size_t)b * NS * 128 + h * 64;
  const float* vb = vg + (size_t)b * NS * 128 + h * 64;

  for (int t = tid; t < KPAD * 8; t += 256) {
    int key = t >> 3, ck = t & 7;
    short8 pk, pv;
    if (key < NS) {
      const float* ksrc = kb + (size_t)key * 128 + ck * 8;
      const float* vsrc = vb + (size_t)key * 128 + ck * 8;
      float4 a = *(const float4*)ksrc;
      float4 c = *(const float4*)(ksrc + 4);
      pk[0]=(short)f2bf(a.x); pk[1]=(short)f2bf(a.y); pk[2]=(short)f2bf(a.z); pk[3]=(short)f2bf(a.w);
      pk[4]=(short)f2bf(c.x); pk[5]=(short)f2bf(c.y); pk[6]=(short)f2bf(c.z); pk[7]=(short)f2bf(c.w);
      float4 e = *(const float4*)vsrc;
      float4 g = *(const float4*)(vsrc + 4);
      pv[0]=(short)f2bf(e.x); pv[1]=(short)f2bf(e.y); pv[2]=(short)f2bf(e.z); pv[3]=(short)f2bf(e.w);
      pv[4]=(short)f2bf(g.x); pv[5]=(short)f2bf(g.y); pv[6]=(short)f2bf(g.z); pv[7]=(short)f2bf(g.w);
    } else {
      pk = (short8)0; pv = (short8)0;
    }
    *(short8*)&ldsKP[key * 64 + ((ck ^ (key & 7)) << 3)] = pk;
    *(short8*)&ldsV[key * 72 + ck * 8] = pv;
  }

  int qrow = chunk * 64 + wv * 16 + l16;
  int qrowc = qrow < ND ? qrow : ND - 1;
  const float* qsrc = q + ((size_t)b * ND + qrowc) * 128 + h * 64 + quad * 8;
  short8 aq0, aq1;
  {
    float4 a = *(const float4*)qsrc;
    float4 c = *(const float4*)(qsrc + 4);
    aq0[0]=(short)f2bf(a.x); aq0[1]=(short)f2bf(a.y); aq0[2]=(short)f2bf(a.z); aq0[3]=(short)f2bf(a.w);
    aq0[4]=(short)f2bf(c.x); aq0[5]=(short)f2bf(c.y); aq0[6]=(short)f2bf(c.z); aq0[7]=(short)f2bf(c.w);
    float4 e = *(const float4*)(qsrc + 32);
    float4 g = *(const float4*)(qsrc + 36);
    aq1[0]=(short)f2bf(e.x); aq1[1]=(short)f2bf(e.y); aq1[2]=(short)f2bf(e.z); aq1[3]=(short)f2bf(e.w);
    aq1[4]=(short)f2bf(g.x); aq1[5]=(short)f2bf(g.y); aq1[6]=(short)f2bf(g.z); aq1[7]=(short)f2bf(g.w);
  }
  __syncthreads();

  f32x4 acc[14];
#pragma unroll
  for (int ct = 0; ct < 14; ++ct) {
    int key = ct * 16 + l16;
    short8 bk0 = *(const short8*)&ldsKP[key * 64 + ((quad ^ (key & 7)) << 3)];
    short8 bk1 = *(const short8*)&ldsKP[key * 64 + (((4 + quad) ^ (key & 7)) << 3)];
    f32x4 z = {0.f, 0.f, 0.f, 0.f};
    z = __builtin_amdgcn_mfma_f32_16x16x32_bf16(aq0, bk0, z, 0, 0, 0);
    z = __builtin_amdgcn_mfma_f32_16x16x32_bf16(aq1, bk1, z, 0, 0, 0);
    acc[ct] = z;
  }

  const float scale = 0.17677669529663687f;  // 32^-0.5
  float rmax[4] = {-1e30f, -1e30f, -1e30f, -1e30f};
#pragma unroll
  for (int ct = 0; ct < 14; ++ct) {
    bool msk = (ct * 16 + l16) >= NS;
#pragma unroll
    for (int r = 0; r < 4; ++r) {
      float sv = msk ? -1e30f : acc[ct][r] * scale;
      acc[ct][r] = sv;
      rmax[r] = fmaxf(rmax[r], sv);
    }
  }
#pragma unroll
  for (int m = 1; m < 16; m <<= 1)
#pragma unroll
    for (int r = 0; r < 4; ++r) rmax[r] = fmaxf(rmax[r], __shfl_xor(rmax[r], m));
  float rsum[4] = {0.f, 0.f, 0.f, 0.f};
#pragma unroll
  for (int ct = 0; ct < 14; ++ct)
#pragma unroll
    for (int r = 0; r < 4; ++r) {
      float e = __expf(acc[ct][r] - rmax[r]);
      acc[ct][r] = e;
      rsum[r] += e;
    }
#pragma unroll
  for (int m = 1; m < 16; m <<= 1)
#pragma unroll
    for (int r = 0; r < 4; ++r) rsum[r] += __shfl_xor(rsum[r], m);
  float rinv[4];
#pragma unroll
  for (int r = 0; r < 4; ++r) rinv[r] = 1.f / rsum[r];

  __syncthreads();

#pragma unroll
  for (int ct = 0; ct < 14; ++ct)
#pragma unroll
    for (int r = 0; r < 4; ++r) {
      int prow = wv * 16 + quad * 4 + r;
      ldsKP[prow * 232 + ct * 16 + l16] = f2bf(acc[ct][r] * rinv[r]);
    }
  __syncthreads();

  f32x4 oacc[4];
#pragma unroll
  for (int ot = 0; ot < 4; ++ot) oacc[ot] = (f32x4){0.f, 0.f, 0.f, 0.f};
#pragma unroll
  for (int kc = 0; kc < 7; ++kc) {
    short8 ap = *(const short8*)&ldsKP[(wv * 16 + l16) * 232 + kc * 32 + quad * 8];
    int keybase = kc * 32 + quad * 8;
#pragma unroll
    for (int ot = 0; ot < 4; ++ot) {
      int dcol = ot * 16 + l16;
      short8 bv;
#pragma unroll
      for (int j = 0; j < 8; ++j) bv[j] = (short)ldsV[(keybase + j) * 72 + dcol];
      oacc[ot] = __builtin_amdgcn_mfma_f32_16x16x32_bf16(ap, bv, oacc[ot], 0, 0, 0);
    }
  }

#pragma unroll
  for (int ot = 0; ot < 4; ++ot)
#pragma unroll
    for (int r = 0; r < 4; ++r) {
      int rowg = chunk * 64 + wv * 16 + quad * 4 + r;
      if (rowg < ND)
        o[((size_t)b * ND + rowg) * 128 + h * 64 + ot * 16 + l16] = oacc[ot][r];
    }
}

// ---------------------------------------------------------------------------
// K8: bilinear grid-sample of pos_embed at pos_down, accumulate into out
// ---------------------------------------------------------------------------
__global__ __launch_bounds__(256) void k_posfeat(const float* __restrict__ pd,
    const float* __restrict__ pe, float* __restrict__ out) {
  int t = blockIdx.x * 256 + threadIdx.x;
  int row = t >> 5, lane = t & 31;
  if (row >= B_ * ND) return;
  float gx = pd[(size_t)2*row] * 2.f - 1.f;
  float gy = pd[(size_t)2*row+1] * 2.f - 1.f;
  float ix = ((gx + 1.f) * 56.f - 1.f) * 0.5f;
  float iy = ((gy + 1.f) * 56.f - 1.f) * 0.5f;
  float x0 = floorf(ix), y0 = floorf(iy);
  float wx1 = ix - x0, wy1 = iy - y0;
  float wx0 = 1.f - wx1, wy0 = 1.f - wy1;
  float4 acc = make_float4(0.f, 0.f, 0.f, 0.f);
#pragma unroll
  for (int cy = 0; cy < 2; ++cy) {
#pragma unroll
    for (int cx = 0; cx < 2; ++cx) {
      float xc = x0 + (float)cx, yc = y0 + (float)cy;
      float wgt = (cx ? wx1 : wx0) * (cy ? wy1 : wy0);
      bool valid = (xc >= 0.f) && (xc < 56.f) && (yc >= 0.f) && (yc < 56.f);
      if (valid) {
        int lin = (int)yc * 56 + (int)xc;
        float4 pv = ((const float4*)(pe + (size_t)lin * 128))[lane];
        acc.x += wgt * pv.x; acc.y += wgt * pv.y;
        acc.z += wgt * pv.z; acc.w += wgt * pv.w;
      }
    }
  }
  float4* op = (float4*)(out + (size_t)row * 128) + lane;
  float4 cur = *op;
  cur.x += acc.x; cur.y += acc.y; cur.z += acc.z; cur.w += acc.w;
  *op = cur;
}

// ---------------------------------------------------------------------------
// launcher
// ---------------------------------------------------------------------------
extern "C" void kernel_launch(void* const* d_in, const int* in_sizes, int n_in,
                              void* d_out, int out_size, void* d_ws, size_t ws_size,
                              hipStream_t stream) {
  const float* x      = (const float*)d_in[0];
  const float* pos    = (const float*)d_in[1];
  const float* pe     = (const float*)d_in[2];
  const float* nu     = (const float*)d_in[3];
  const float* norm_g = (const float*)d_in[4];
  const float* norm_b = (const float*)d_in[5];
  const float* conf_w = (const float*)d_in[6];
  const float* conf_b = (const float*)d_in[7];
  const float* n1g    = (const float*)d_in[8];
  const float* n1b    = (const float*)d_in[9];
  const float* q_w    = (const float*)d_in[10];
  const float* k_w    = (const float*)d_in[11];
  const float* v_w    = (const float*)d_in[12];
  const float* proj_w = (const float*)d_in[13];
  const float* proj_b = (const float*)d_in[14];
  const float* sr_w   = (const float*)d_in[15];
  const float* sr_b   = (const float*)d_in[16];
  const float* srn_g  = (const float*)d_in[17];
  const float* srn_b  = (const float*)d_in[18];
  const float* fc_w   = (const float*)d_in[19];
  const float* fc_b   = (const float*)d_in[20];
  const float* n2g    = (const float*)d_in[21];
  const float* n2b    = (const float*)d_in[22];
  const float* fc1_w  = (const float*)d_in[23];
  const float* fc1_b  = (const float*)d_in[24];
  const float* fc2_w  = (const float*)d_in[25];
  const float* fc2_b  = (const float*)d_in[26];

  char* ws = (char*)d_ws;
  // workspace layout (bytes); total 190,578,688 (unchanged)
  double*         scores = (double*)(ws + 0);                //  1,580,544
  int*            idx    = (int*)(ws + 1605632);             //    200,704
  float*          xd     = (float*)(ws + 1835008);           // 13,647,872
  float*          xn     = (float*)(ws + 15728640);          // 13,647,872
  float*          pd     = (float*)(ws + 29491200);          //    426,496
  float*          qb     = (float*)(ws + 30408704);          // 27,295,744; T alias; later q/O2
  float*          ob     = (float*)(ws + 58720256);          // 27,295,744; T tail alias; later xn2
  float*          wt     = (float*)(ws + 86507520);          //    262,144
  unsigned short* W1p    = (unsigned short*)(ws + 86769664); //    131,072
  unsigned short* W2p    = (unsigned short*)(ws + 86900736); //    131,072 (ends 87,031,808)
  char*           big    = ws + 87031808;                    // 103,546,880 region
  float*          S      = (float*)big;                      // 52,183,040 (dead after coef+transpose)
  float*          T      = qb;                               // 51,380,224 channel-major planes (dead after filter2)
  float*          Kc     = (float*)(big + 52183040);         //  7,225,344 coefficient planes (dead after filter2)
  float*          P      = (float*)big;                      // 51,380,224 (reuses dead S; dead after conv)
  float*          xs_c   = (float*)(big + 59408384);         //  3,211,264
  float*          xs_n   = (float*)(big + 62619648);         //  3,211,264
  float*          kbuf   = (float*)(big + 65830912);         //  6,422,528
  float*          vbuf   = (float*)(big + 72253440);         //  6,422,528 (ends 78,675,968)
  int*            counts = (int*)(big + 78675968);           //    790,272 (dead after rankw; before S region is ever written... S memset only covers first 52MB, no overlap)
  float*          O2     = qb;
  float*          xn2    = ob;
  float*          out    = (float*)d_out;

  // 1) f64 conf+gumbel scores
  k_conf<<<(B_ * N_) / 256, 256, 0, stream>>>(x, norm_g, norm_b, conf_w, conf_b, nu, scores);
  // 2) top-784 per batch: distributed rank-by-count (2-D split) + write pass
  hipMemsetAsync(counts, 0, (size_t)B_ * NREST * sizeof(int), stream);
  k_rank<<<B_ * NEC * NJC, 256, 0, stream>>>(scores, counts);
  k_rankw<<<(B_ * NREST + 255) / 256, 256, 0, stream>>>(counts, idx);
  // 3) gather + LN(norm1)
  k_gather_ln<<<(B_ * ND + 255) / 256, 256, 0, stream>>>(x, pos, idx, n1g, n1b, xd, xn, pd);
  // 4) token2map scatter (wave-per-token, coalesced atomics, f64 binning)
  hipMemsetAsync(S, 0, (size_t)B_ * HW * 65 * sizeof(float), stream);
  k_scatter<<<(B_ * N_ * 64) / 256, 256, 0, stream>>>(x, n1g, n1b, pos, S);
  // 5) gaussian reconstruct, 3 passes
  k_coef<<<BHW / 256, 256, 0, stream>>>(S, Kc);
  k_transpose<<<BHW / 64, 256, 0, stream>>>(S, T);
  k_filter2<<<B_ * 64, 256, 0, stream>>>(T, Kc, P);
  // 6) conv weights transpose + MLP weight pack; conv-as-GEMM; srnorm
  k_wt<<<(1024 * 64) / 256, 256, 0, stream>>>(sr_w, wt);
  k_wpack<<<65536 / 256, 256, 0, stream>>>(fc1_w, fc2_w, W1p, W2p);
  dim3 g_conv(NS * B_ / 64, 1);
  k_gemm<<<g_conv, 256, 0, stream>>>(P, wt, sr_b, nullptr, xs_c, B_ * NS, 64, 1024);
  k_ln64<<<(B_ * NS + 255) / 256, 256, 0, stream>>>(xs_c, srn_g, srn_b, xs_n, B_ * NS);
  // 7) k, v, q projections (q GEMM overwrites T region -- T is dead by now)
  dim3 g_kv(B_ * NS / 64, 2);
  k_gemm<<<g_kv, 256, 0, stream>>>(xs_n, k_w, nullptr, nullptr, kbuf, B_ * NS, 128, 64);
  k_gemm<<<g_kv, 256, 0, stream>>>(xs_n, v_w, nullptr, nullptr, vbuf, B_ * NS, 128, 64);
  dim3 g_row(B_ * ND / 64, 2);
  k_gemm<<<g_row, 256, 0, stream>>>(xn, q_w, nullptr, nullptr, qb, B_ * ND, 128, 64);
  // 8) attention (MFMA bf16)
  k_attn<<<B_ * 2 * 14, 256, 0, stream>>>(qb, kbuf, vbuf, ob);
  // 9) x2 = x_down@fc_w + fc_b + (o@proj_w + proj_b)  -> d_out
  k_gemm<<<g_row, 256, 0, stream>>>(ob, proj_w, proj_b, nullptr, O2, B_ * ND, 128, 128);
  k_gemm<<<g_row, 256, 0, stream>>>(xd, fc_w, fc_b, O2, out, B_ * ND, 128, 64);
  // 10) MLP: LN128 then MFMA fused fc1+gelu+fc2 (accumulates into out)
  k_ln128<<<(B_ * ND + 255) / 256, 256, 0, stream>>>(out, n2g, n2b, xn2, B_ * ND);
  k_mlp<<<B_ * ND / 64, 256, 0, stream>>>(xn2, W1p, fc1_b, W2p, fc2_b, out);
  // 11) + pos_feat (bilinear grid sample)
  k_posfeat<<<(B_ * ND * 32) / 256, 256, 0, stream>>>(pd, pe, out);
}

// Round 4
// 694.708 us; speedup vs baseline: 1.2937x; 1.1800x over previous
//
#include <hip/hip_runtime.h>
#include <math.h>

#define DEVINL __device__ __forceinline__

constexpr int B_ = 64;
constexpr int N_ = 3136;
constexpr int C_ = 64;        // DIM
constexpr int NG = 49;        // N_grid
constexpr int NSAMP = 784;    // SAMPLE_NUM
constexpr int ND = NG + NSAMP;     // 833
constexpr int NREST = N_ - NG;     // 3087
constexpr int H_ = 56, W_ = 56;
constexpr int HW = H_ * W_;        // 3136
constexpr int BHW = B_ * HW;       // 200704
constexpr int NS = 14 * 14;        // 196 kv tokens
constexpr int KPAD = 224;          // 196 padded to 7*32
constexpr float LN_EPS = 1e-5f;
constexpr float EPS6 = 1e-6f;

typedef __attribute__((ext_vector_type(8))) short short8;
typedef __attribute__((ext_vector_type(4))) float f32x4;

DEVINL unsigned short f2bf(float f) {
  unsigned int u = __float_as_uint(f);
  unsigned int r = u + 0x7FFFu + ((u >> 16) & 1u);
  return (unsigned short)(r >> 16);
}

// ---------------------------------------------------------------------------
// K1: conf scores in FP64 (discrete top-k decision must match f64 np ref)
// ---------------------------------------------------------------------------
__global__ __launch_bounds__(256) void k_conf(
    const float* __restrict__ x, const float* __restrict__ ng, const float* __restrict__ nb,
    const float* __restrict__ cw, const float* __restrict__ cb,
    const float* __restrict__ nu, double* __restrict__ scores) {
  int t = blockIdx.x * 256 + threadIdx.x;
  if (t >= B_ * N_) return;
  int b = t / N_, n = t - b * N_;
  if (n < NG) return;
  const float4* row = (const float4*)(x + (size_t)t * C_);
  float v[C_];
#pragma unroll
  for (int i = 0; i < 16; ++i) {
    float4 r = row[i];
    v[4*i] = r.x; v[4*i+1] = r.y; v[4*i+2] = r.z; v[4*i+3] = r.w;
  }
  double sd = 0.0;
#pragma unroll
  for (int i = 0; i < C_; ++i) sd += (double)v[i];
  double md = sd * (1.0/64.0);
  double vd = 0.0;
#pragma unroll
  for (int i = 0; i < C_; ++i) { double d = (double)v[i] - md; vd += d * d; }
  vd *= (1.0/64.0);
  double rsd = 1.0 / sqrt(vd + 1e-5);
  double conf = (double)cb[0];
#pragma unroll
  for (int i = 0; i < C_; ++i) {
    double xnv = ((double)v[i] - md) * rsd;
    conf += (xnv * (double)ng[i] + (double)nb[i]) * (double)cw[i];
  }
  double u = (double)nu[(size_t)b * NREST + (n - NG)];
  double noise = -log(-log(u + 1e-6) + 1e-6);
  scores[(size_t)b * NREST + (n - NG)] = conf + noise;
}

// ---------------------------------------------------------------------------
// K2 (ROUND-10): exact top-784 via counting-sort rank. One block per batch.
// (1) f32 projection of the f64 key is MONOTONE, so strict f32 > implies
//     strict f64 >; linear quantization into 2048 bins partitions exactly.
// (2) histogram + suffix scan  -> bstart[b] = #elements in strictly-better
//     bins (exact, since cross-bin order is strict).
// (3) within-bin rank resolved with FULL f64 compares + index tie-break
//     (avg bin occupancy 3087/2048 = 1.5).
// rank(e) = #{j: s_j > s_e} + #{j: s_j == s_e && j < e}  == jax.lax.top_k
// order; idx[rank]=e for rank<784. All-equal degenerate range -> one bin,
// O(N^2) fallback (correct, just slow; never hit with random data).
// ---------------------------------------------------------------------------
constexpr int NB = 2048;

__global__ __launch_bounds__(256) void k_topk2(const double* __restrict__ scores,
                                               int* __restrict__ idx) {
  __shared__ double sk[NREST];              // 24,696 B
  __shared__ int hist[NB];                  //  8,192 B
  __shared__ int bstart[NB];                //  8,192 B
  __shared__ int fill[NB];                  //  8,192 B
  __shared__ unsigned short order[NREST];   //  6,174 B
  __shared__ float redmin[256], redmax[256];//  2,048 B
  __shared__ int scanbuf[256];              //  1,024 B   (~58.5 KB total)
  int b = blockIdx.x, tid = threadIdx.x;
  const double* sc = scores + (size_t)b * NREST;
  float lmin = 3.4e38f, lmax = -3.4e38f;
  for (int i = tid; i < NREST; i += 256) {
    double d = sc[i];
    sk[i] = d;
    float f = (float)d;
    lmin = fminf(lmin, f); lmax = fmaxf(lmax, f);
  }
  for (int i = tid; i < NB; i += 256) hist[i] = 0;
  redmin[tid] = lmin; redmax[tid] = lmax;
  __syncthreads();
  for (int s = 128; s > 0; s >>= 1) {
    if (tid < s) {
      redmin[tid] = fminf(redmin[tid], redmin[tid + s]);
      redmax[tid] = fmaxf(redmax[tid], redmax[tid + s]);
    }
    __syncthreads();
  }
  float fmn = redmin[0];
  float scale = (float)NB / fmaxf(redmax[0] - fmn, 1e-30f);
  // histogram
  for (int i = tid; i < NREST; i += 256) {
    float f = (float)sk[i];
    int bn = (int)((f - fmn) * scale);
    bn = bn < 0 ? 0 : (bn > NB - 1 ? NB - 1 : bn);
    atomicAdd(&hist[bn], 1);
  }
  __syncthreads();
  // suffix scan: bstart[bin] = sum over strictly-higher bins.
  int base = tid * 8;          // this thread owns bins [base, base+8)
  int s_t = 0;
#pragma unroll
  for (int i = 0; i < 8; ++i) s_t += hist[base + i];
  scanbuf[tid] = s_t;
  __syncthreads();
  int val = s_t;
  for (int off = 1; off < 256; off <<= 1) {
    int other = (tid + off < 256) ? scanbuf[tid + off] : 0;
    __syncthreads();
    val += other;
    scanbuf[tid] = val;
    __syncthreads();
  }
  int run = val - s_t;         // sum over threads t' > tid
#pragma unroll
  for (int i = 7; i >= 0; --i) {
    bstart[base + i] = run;
    run += hist[base + i];
  }
  __syncthreads();
  for (int i = tid; i < NB; i += 256) fill[i] = bstart[i];
  __syncthreads();
  // scatter element ids into bin-grouped order[]
  for (int i = tid; i < NREST; i += 256) {
    float f = (float)sk[i];
    int bn = (int)((f - fmn) * scale);
    bn = bn < 0 ? 0 : (bn > NB - 1 ? NB - 1 : bn);
    int pos = atomicAdd(&fill[bn], 1);
    order[pos] = (unsigned short)i;
  }
  __syncthreads();
  // exact rank = bstart[bin] + within-bin f64 rank; write winners
  for (int i = tid; i < NREST; i += 256) {
    double ke = sk[i];
    float f = (float)ke;
    int bn = (int)((f - fmn) * scale);
    bn = bn < 0 ? 0 : (bn > NB - 1 ? NB - 1 : bn);
    int st = bstart[bn], m = hist[bn];
    int r = st;
    for (int p = st; p < st + m; ++p) {
      int j = order[p];
      double kj = sk[j];
      r += (int)((kj > ke) | ((kj == ke) & (j < i)));
    }
    if (r < NSAMP) idx[(size_t)b * NSAMP + r] = i;
  }
}

// ---------------------------------------------------------------------------
// K3: gather x_down/pos_down rows; LayerNorm(x_down, norm1) -> xn
// ---------------------------------------------------------------------------
__global__ __launch_bounds__(256) void k_gather_ln(
    const float* __restrict__ x, const float* __restrict__ pos, const int* __restrict__ idx,
    const float* __restrict__ n1g, const float* __restrict__ n1b,
    float* __restrict__ xd, float* __restrict__ xn, float* __restrict__ pd) {
  int t = blockIdx.x * 256 + threadIdx.x;
  if (t >= B_ * ND) return;
  int b = t / ND, r = t - b * ND;
  int srcn = (r < NG) ? r : (NG + idx[(size_t)b * NSAMP + (r - NG)]);
  const float4* row = (const float4*)(x + ((size_t)b * N_ + srcn) * C_);
  float4* xdr = (float4*)(xd + (size_t)t * C_);
  float v[C_];
  float s = 0.f, ss = 0.f;
#pragma unroll
  for (int i = 0; i < 16; ++i) {
    float4 rr = row[i];
    xdr[i] = rr;
    v[4*i] = rr.x; v[4*i+1] = rr.y; v[4*i+2] = rr.z; v[4*i+3] = rr.w;
    s += rr.x + rr.y + rr.z + rr.w;
    ss += rr.x*rr.x + rr.y*rr.y + rr.z*rr.z + rr.w*rr.w;
  }
  float m = s * (1.f/64.f);
  float var = ss * (1.f/64.f) - m*m;
  float rs = rsqrtf(var + LN_EPS);
#pragma unroll
  for (int i = 0; i < C_; ++i)
    xn[(size_t)t * C_ + i] = (v[i] - m) * rs * n1g[i] + n1b[i];
  pd[(size_t)2*t]   = pos[((size_t)b * N_ + srcn) * 2];
  pd[(size_t)2*t+1] = pos[((size_t)b * N_ + srcn) * 2 + 1];
}

// ---------------------------------------------------------------------------
// K4: scatter: one WAVE per token, lane = channel; coalesced atomics.
// ---------------------------------------------------------------------------
__global__ __launch_bounds__(256) void k_scatter(
    const float* __restrict__ x, const float* __restrict__ n1g, const float* __restrict__ n1b,
    const float* __restrict__ pos, float* __restrict__ S) {
  int gt = blockIdx.x * 256 + threadIdx.x;
  int tok = gt >> 6, lane = gt & 63;
  if (tok >= B_ * N_) return;
  int b = tok / N_;
  float v = x[(size_t)tok * C_ + lane];
  float s = v, ss = v * v;
#pragma unroll
  for (int m = 32; m > 0; m >>= 1) {
    s += __shfl_xor(s, m);
    ss += __shfl_xor(ss, m);
  }
  float mean = s * (1.f/64.f);
  float var = ss * (1.f/64.f) - mean * mean;
  float rs = rsqrtf(var + LN_EPS);
  double px = fmin(fmax((double)pos[(size_t)2*tok],   0.0), 1.0) * (double)(W_ - 1);
  double py = fmin(fmax((double)pos[(size_t)2*tok+1], 0.0), 1.0) * (double)(H_ - 1);
  int xi = (int)rint(px), yi = (int)rint(py);
  float* base = S + ((size_t)b * HW + yi * W_ + xi) * 65;
  atomicAdd(base + lane, (v - mean) * rs * n1g[lane] + n1b[lane]);
  if (lane == 0) atomicAdd(base + 64, 1.f);
}

// ---------------------------------------------------------------------------
// K5b (now FIRST): transpose S[p][65] -> channel planes T[b][c][HW] and
// emit the mask plane M[b*HW+p] contiguously (for coalesced k_coef reads).
// ---------------------------------------------------------------------------
__global__ __launch_bounds__(256) void k_transpose(const float* __restrict__ S,
                                                   float* __restrict__ T,
                                                   float* __restrict__ M) {
  __shared__ float ls[64 * 65];
  int g0 = blockIdx.x * 64;            // global pixel base (batch-major)
  int b = g0 / HW, p0 = g0 - b * HW;
  const float4* src = (const float4*)(S + (size_t)g0 * 65);
  for (int i = threadIdx.x; i < (64 * 65) / 4; i += 256)
    *(float4*)&ls[i * 4] = src[i];
  __syncthreads();
  for (int i = threadIdx.x; i < 64 * 64; i += 256) {
    int c = i >> 6, px = i & 63;
    T[((size_t)(b * 64 + c)) * HW + p0 + px] = ls[px * 65 + c];
  }
  for (int i = threadIdx.x; i < 64; i += 256)
    M[(size_t)g0 + i] = ls[i * 65 + 64];
}

// ---------------------------------------------------------------------------
// K5a: per-pixel 3x3 coefficient planes, mask read from contiguous M plane.
// ---------------------------------------------------------------------------
__global__ __launch_bounds__(256) void k_coef(const float* __restrict__ M, float* __restrict__ Kc) {
  int t = blockIdx.x * 256 + threadIdx.x;
  if (t >= BHW) return;
  int b = t / HW, p = t - b * HW;
  int y = p / W_, x = p - y * W_;
  const float* Mb = M + (size_t)b * HW;
  const float e1 = 0.882496902584595f;   // exp(-1/8)
  const float e2 = 0.778800783071405f;   // exp(-1/4)
  const float Z = 1.f + 4.f * (e1 + e2);
  float m0 = Mb[p];
  float mb0 = m0 > 0.f ? 1.f : 0.f;
  float cfac = mb0 / (m0 + EPS6);
  float sc[9];
  float mi = 0.f;
  int q = 0;
#pragma unroll
  for (int dy = -1; dy <= 1; ++dy) {
#pragma unroll
    for (int dx = -1; dx <= 1; ++dx) {
      int ny = y + dy, nx = x + dx;
      bool in = (ny >= 0 && ny < H_ && nx >= 0 && nx < W_);
      float w = ((dx == 0 && dy == 0) ? 1.f : ((dx*dx + dy*dy) == 1 ? e1 : e2)) / Z;
      float mm = in ? Mb[ny * W_ + nx] : 0.f;
      float mb = mm > 0.f ? 1.f : 0.f;
      mi += w * mb;
      sc[q] = in ? (w * mb / (mm + EPS6)) : 0.f;
      ++q;
    }
  }
  float outer = (1.f - mb0) * ((mi > 0.f ? 1.f : 0.f) / (mi + EPS6));
#pragma unroll
  for (int qq = 0; qq < 9; ++qq) {
    float cq = outer * sc[qq];
    if (qq == 4) cq += cfac;
    Kc[(size_t)qq * BHW + t] = cq;
  }
}

// ---------------------------------------------------------------------------
// K5c: spatially-varying 3x3 conv on channel planes -> conv-patch layout P.
// ---------------------------------------------------------------------------
__global__ __launch_bounds__(256) void k_filter2(
    const float* __restrict__ T, const float* __restrict__ Kc, float* __restrict__ P) {
  int plane = blockIdx.x;              // b*64 + c
  int b = plane >> 6, c = plane & 63;
  int tid = threadIdx.x;
  const float* Tp = T + (size_t)plane * HW;
  const float* Kb = Kc + (size_t)b * HW;
  for (int p0 = 0; p0 < HW; p0 += 256) {
    int p = p0 + tid;
    if (p < HW) {
      int y = p / W_, x = p - y * W_;
      float acc = 0.f;
      int q = 0;
#pragma unroll
      for (int dy = -1; dy <= 1; ++dy) {
#pragma unroll
        for (int dx = -1; dx <= 1; ++dx) {
          int ny = y + dy; ny = ny < 0 ? 0 : (ny > H_ - 1 ? H_ - 1 : ny);
          int nx = x + dx; nx = nx < 0 ? 0 : (nx > W_ - 1 ? W_ - 1 : nx);
          acc += Kb[(size_t)q * BHW + p] * Tp[ny * W_ + nx];
          ++q;
        }
      }
      int j = (y >> 2) * 14 + (x >> 2);
      int colb = ((y & 3) << 2) + (x & 3);
      P[((size_t)(b * NS + j)) * 1024 + c * 16 + colb] = acc;
    }
  }
}

// ---------------------------------------------------------------------------
// K6: transpose sr_w (co,ci,ky,kx) -> w_t[kk=ci*16+ky*4+kx][co]
// ---------------------------------------------------------------------------
__global__ __launch_bounds__(256) void k_wt(const float* __restrict__ srw, float* __restrict__ wt) {
  int t = blockIdx.x * 256 + threadIdx.x;
  if (t >= 1024 * 64) return;
  int kk = t >> 6, co = t & 63;
  int ci = kk >> 4, r = kk & 15;
  wt[t] = srw[(((size_t)co * 64 + ci) << 4) + r];
}

// ---------------------------------------------------------------------------
// K6b: pack fc1/fc2 weights into B-frag-contiguous bf16 layout
// ---------------------------------------------------------------------------
__global__ __launch_bounds__(256) void k_wpack(const float* __restrict__ W1, const float* __restrict__ W2,
    unsigned short* __restrict__ W1p, unsigned short* __restrict__ W2p) {
  int t = blockIdx.x * 256 + threadIdx.x;
  if (t >= 65536) return;
  {
    int j = t & 7;
    int n = (t >> 3) & 511;
    int qk = t >> 12;            // 0..15
    int quad = qk & 3, kc = qk >> 2;
    int k = kc * 32 + quad * 8 + j;
    W1p[t] = f2bf(W1[(size_t)k * 512 + n]);
  }
  {
    int j = t & 7;
    int n = (t >> 3) & 127;
    int qk = t >> 10;            // 0..63
    int quad = qk & 3, kg = qk >> 2;
    int k = kg * 32 + quad * 8 + j;
    W2p[t] = f2bf(W2[(size_t)k * 128 + n]);
  }
}

// ---------------------------------------------------------------------------
// Tiled fp32 GEMM: C[M,N] = A[M,K] @ B[K,N] (+bias)(+add)
// ---------------------------------------------------------------------------
__global__ __launch_bounds__(256) void k_gemm(
    const float* __restrict__ A, const float* __restrict__ Bw,
    const float* __restrict__ bias, const float* __restrict__ add,
    float* __restrict__ Cout, int M, int N, int K) {
  __shared__ float sA[16][68];
  __shared__ float sB[16][64];
  int bm = blockIdx.x * 64, bn = blockIdx.y * 64;
  int tid = threadIdx.x;
  int tx = tid & 15, ty = tid >> 4;
  float acc[4][4] = {{0.f}};
  for (int k0 = 0; k0 < K; k0 += 16) {
    int e = tid << 2;
    int am = e >> 4, ak = e & 15;
    float4 a4 = *(const float4*)(A + (size_t)(bm + am) * K + k0 + ak);
    sA[ak + 0][am] = a4.x; sA[ak + 1][am] = a4.y; sA[ak + 2][am] = a4.z; sA[ak + 3][am] = a4.w;
    int bk = e >> 6, nn = e & 63;
    float4 b4 = *(const float4*)(Bw + (size_t)(k0 + bk) * N + bn + nn);
    *(float4*)&sB[bk][nn] = b4;
    __syncthreads();
#pragma unroll
    for (int kk = 0; kk < 16; ++kk) {
      float a[4], bb[4];
#pragma unroll
      for (int i = 0; i < 4; ++i) a[i] = sA[kk][ty * 4 + i];
#pragma unroll
      for (int i = 0; i < 4; ++i) bb[i] = sB[kk][tx * 4 + i];
#pragma unroll
      for (int i = 0; i < 4; ++i)
#pragma unroll
        for (int jj = 0; jj < 4; ++jj) acc[i][jj] += a[i] * bb[jj];
    }
    __syncthreads();
  }
#pragma unroll
  for (int i = 0; i < 4; ++i) {
    int row = bm + ty * 4 + i;
#pragma unroll
    for (int jj = 0; jj < 4; ++jj) {
      int col = bn + tx * 4 + jj;
      float v = acc[i][jj];
      if (bias) v += bias[col];
      if (add) v += add[(size_t)row * N + col];
      Cout[(size_t)row * N + col] = v;
    }
  }
}

// ---------------------------------------------------------------------------
// K-MLP: MFMA bf16. out += gelu(A@W1+b1)@W2+b2.
// ---------------------------------------------------------------------------
__global__ __launch_bounds__(256) void k_mlp(
    const float* __restrict__ A, const unsigned short* __restrict__ W1p, const float* __restrict__ b1,
    const unsigned short* __restrict__ W2p, const float* __restrict__ b2, float* __restrict__ out) {
  __shared__ __align__(16) unsigned short sA[64 * 128];
  __shared__ __align__(16) unsigned short sH[4][16 * 128];
  int bm = blockIdx.x * 64;
  int tid = threadIdx.x;
  int wv = tid >> 6, lane = tid & 63, quad = lane >> 4, l16 = lane & 15;

  for (int t = tid; t < 64 * 16; t += 256) {
    int row = t >> 4, ck = t & 15;
    const float* src = A + (size_t)(bm + row) * 128 + ck * 8;
    float4 a = *(const float4*)src;
    float4 c = *(const float4*)(src + 4);
    short8 p;
    p[0]=(short)f2bf(a.x); p[1]=(short)f2bf(a.y); p[2]=(short)f2bf(a.z); p[3]=(short)f2bf(a.w);
    p[4]=(short)f2bf(c.x); p[5]=(short)f2bf(c.y); p[6]=(short)f2bf(c.z); p[7]=(short)f2bf(c.w);
    *(short8*)&sA[row * 128 + (((ck ^ row) & 15) << 3)] = p;
  }
  __syncthreads();

  f32x4 oacc[8];
#pragma unroll
  for (int ct = 0; ct < 8; ++ct) oacc[ct] = (f32x4){0.f, 0.f, 0.f, 0.f};

  for (int hc = 0; hc < 4; ++hc) {
    f32x4 acc1[8];
#pragma unroll
    for (int ct = 0; ct < 8; ++ct) acc1[ct] = (f32x4){0.f, 0.f, 0.f, 0.f};
#pragma unroll
    for (int kc = 0; kc < 4; ++kc) {
      int row = wv * 16 + l16;
      int ck = kc * 4 + quad;
      short8 af = *(const short8*)&sA[row * 128 + (((ck ^ row) & 15) << 3)];
#pragma unroll
      for (int ct = 0; ct < 8; ++ct) {
        int n = hc * 128 + ct * 16 + l16;
        short8 bf = *(const short8*)&W1p[(((size_t)kc * 4 + quad) * 512 + n) << 3];
        acc1[ct] = __builtin_amdgcn_mfma_f32_16x16x32_bf16(af, bf, acc1[ct], 0, 0, 0);
      }
    }
    __syncthreads();   // prior GEMM2 reads of sH done (all waves)
#pragma unroll
    for (int ct = 0; ct < 8; ++ct)
#pragma unroll
      for (int r = 0; r < 4; ++r) {
        float v = acc1[ct][r] + b1[hc * 128 + ct * 16 + l16];
        v = 0.5f * v * (1.f + erff(v * 0.70710678118654752f));
        int rit = quad * 4 + r;
        int col = ct * 16 + l16;
        int ck = col >> 3;
        sH[wv][rit * 128 + (((ck ^ rit) & 15) << 3) + (col & 7)] = f2bf(v);
      }
    __syncthreads();   // H visible
#pragma unroll
    for (int kc = 0; kc < 4; ++kc) {
      int ck = kc * 4 + quad;
      short8 hf = *(const short8*)&sH[wv][l16 * 128 + (((ck ^ l16) & 15) << 3)];
      int kg = hc * 4 + kc;
#pragma unroll
      for (int ct = 0; ct < 8; ++ct) {
        int n = ct * 16 + l16;
        short8 bf = *(const short8*)&W2p[(((size_t)kg * 4 + quad) * 128 + n) << 3];
        oacc[ct] = __builtin_amdgcn_mfma_f32_16x16x32_bf16(hf, bf, oacc[ct], 0, 0, 0);
      }
    }
  }
#pragma unroll
  for (int ct = 0; ct < 8; ++ct)
#pragma unroll
    for (int r = 0; r < 4; ++r) {
      int row = bm + wv * 16 + quad * 4 + r;
      int col = ct * 16 + l16;
      out[(size_t)row * 128 + col] += oacc[ct][r] + b2[col];
    }
}

// ---------------------------------------------------------------------------
// LayerNorm kernels (dim 128 / dim 64), one thread per row
// ---------------------------------------------------------------------------
__global__ __launch_bounds__(256) void k_ln128(const float* __restrict__ in, const float* __restrict__ g,
    const float* __restrict__ bb, float* __restrict__ out, int rows) {
  int t = blockIdx.x * 256 + threadIdx.x;
  if (t >= rows) return;
  const float4* row = (const float4*)(in + (size_t)t * 128);
  float4 v[32];
  float s = 0.f, ss = 0.f;
#pragma unroll
  for (int i = 0; i < 32; ++i) {
    float4 r = row[i]; v[i] = r;
    s += r.x + r.y + r.z + r.w;
    ss += r.x*r.x + r.y*r.y + r.z*r.z + r.w*r.w;
  }
  float m = s * (1.f/128.f);
  float var = ss * (1.f/128.f) - m*m;
  float rs = rsqrtf(var + LN_EPS);
  float4* orow = (float4*)(out + (size_t)t * 128);
#pragma unroll
  for (int i = 0; i < 32; ++i) {
    float4 r = v[i];
    float4 o;
    o.x = (r.x - m) * rs * g[4*i+0] + bb[4*i+0];
    o.y = (r.y - m) * rs * g[4*i+1] + bb[4*i+1];
    o.z = (r.z - m) * rs * g[4*i+2] + bb[4*i+2];
    o.w = (r.w - m) * rs * g[4*i+3] + bb[4*i+3];
    orow[i] = o;
  }
}

__global__ __launch_bounds__(256) void k_ln64(const float* __restrict__ in, const float* __restrict__ g,
    const float* __restrict__ bb, float* __restrict__ out, int rows) {
  int t = blockIdx.x * 256 + threadIdx.x;
  if (t >= rows) return;
  const float4* row = (const float4*)(in + (size_t)t * 64);
  float v[64];
  float s = 0.f, ss = 0.f;
#pragma unroll
  for (int i = 0; i < 16; ++i) {
    float4 r = row[i];
    v[4*i] = r.x; v[4*i+1] = r.y; v[4*i+2] = r.z; v[4*i+3] = r.w;
    s += r.x + r.y + r.z + r.w;
    ss += r.x*r.x + r.y*r.y + r.z*r.z + r.w*r.w;
  }
  float m = s * (1.f/64.f);
  float var = ss * (1.f/64.f) - m*m;
  float rs = rsqrtf(var + LN_EPS);
#pragma unroll
  for (int i = 0; i < 64; ++i)
    out[(size_t)t * 64 + i] = (v[i] - m) * rs * g[i] + bb[i];
}

// ---------------------------------------------------------------------------
// K7: MFMA attention, unchanged.
// ---------------------------------------------------------------------------
__global__ __launch_bounds__(256) void k_attn(const float* __restrict__ q,
    const float* __restrict__ kg, const float* __restrict__ vg, float* __restrict__ o) {
  __shared__ __align__(16) unsigned short ldsKP[14848];
  __shared__ __align__(16) unsigned short ldsV[16128];
  int blk = blockIdx.x;
  int chunk = blk % 14;
  int bh = blk / 14;
  int h = bh & 1, b = bh >> 1;
  int tid = threadIdx.x;
  int wv = tid >> 6, lane = tid & 63;
  int quad = lane >> 4, l16 = lane & 15;

  const float* kb = kg + (size_t)b * NS * 128 + h * 64;
  const float* vb = vg + (size_t)b * NS * 128 + h * 64;

  for (int t = tid; t < KPAD * 8; t += 256) {
    int key = t >> 3, ck = t & 7;
    short8 pk, pv;
    if (key < NS) {
      const float* ksrc = kb + (size_t)key * 128 + ck * 8;
      const float* vsrc = vb + (size_t)key * 128 + ck * 8;
      float4 a = *(const float4*)ksrc;
      float4 c = *(const float4*)(ksrc + 4);
      pk[0]=(short)f2bf(a.x); pk[1]=(short)f2bf(a.y); pk[2]=(short)f2bf(a.z); pk[3]=(short)f2bf(a.w);
      pk[4]=(short)f2bf(c.x); pk[5]=(short)f2bf(c.y); pk[6]=(short)f2bf(c.z); pk[7]=(short)f2bf(c.w);
      float4 e = *(const float4*)vsrc;
      float4 g = *(const float4*)(vsrc + 4);
      pv[0]=(short)f2bf(e.x); pv[1]=(short)f2bf(e.y); pv[2]=(short)f2bf(e.z); pv[3]=(short)f2bf(e.w);
      pv[4]=(short)f2bf(g.x); pv[5]=(short)f2bf(g.y); pv[6]=(short)f2bf(g.z); pv[7]=(short)f2bf(g.w);
    } else {
      pk = (short8)0; pv = (short8)0;
    }
    *(short8*)&ldsKP[key * 64 + ((ck ^ (key & 7)) << 3)] = pk;
    *(short8*)&ldsV[key * 72 + ck * 8] = pv;
  }

  int qrow = chunk * 64 + wv * 16 + l16;
  int qrowc = qrow < ND ? qrow : ND - 1;
  const float* qsrc = q + ((size_t)b * ND + qrowc) * 128 + h * 64 + quad * 8;
  short8 aq0, aq1;
  {
    float4 a = *(const float4*)qsrc;
    float4 c = *(const float4*)(qsrc + 4);
    aq0[0]=(short)f2bf(a.x); aq0[1]=(short)f2bf(a.y); aq0[2]=(short)f2bf(a.z); aq0[3]=(short)f2bf(a.w);
    aq0[4]=(short)f2bf(c.x); aq0[5]=(short)f2bf(c.y); aq0[6]=(short)f2bf(c.z); aq0[7]=(short)f2bf(c.w);
    float4 e = *(const float4*)(qsrc + 32);
    float4 g = *(const float4*)(qsrc + 36);
    aq1[0]=(short)f2bf(e.x); aq1[1]=(short)f2bf(e.y); aq1[2]=(short)f2bf(e.z); aq1[3]=(short)f2bf(e.w);
    aq1[4]=(short)f2bf(g.x); aq1[5]=(short)f2bf(g.y); aq1[6]=(short)f2bf(g.z); aq1[7]=(short)f2bf(g.w);
  }
  __syncthreads();

  f32x4 acc[14];
#pragma unroll
  for (int ct = 0; ct < 14; ++ct) {
    int key = ct * 16 + l16;
    short8 bk0 = *(const short8*)&ldsKP[key * 64 + ((quad ^ (key & 7)) << 3)];
    short8 bk1 = *(const short8*)&ldsKP[key * 64 + (((4 + quad) ^ (key & 7)) << 3)];
    f32x4 z = {0.f, 0.f, 0.f, 0.f};
    z = __builtin_amdgcn_mfma_f32_16x16x32_bf16(aq0, bk0, z, 0, 0, 0);
    z = __builtin_amdgcn_mfma_f32_16x16x32_bf16(aq1, bk1, z, 0, 0, 0);
    acc[ct] = z;
  }

  const float scale = 0.17677669529663687f;  // 32^-0.5
  float rmax[4] = {-1e30f, -1e30f, -1e30f, -1e30f};
#pragma unroll
  for (int ct = 0; ct < 14; ++ct) {
    bool msk = (ct * 16 + l16) >= NS;
#pragma unroll
    for (int r = 0; r < 4; ++r) {
      float sv = msk ? -1e30f : acc[ct][r] * scale;
      acc[ct][r] = sv;
      rmax[r] = fmaxf(rmax[r], sv);
    }
  }
#pragma unroll
  for (int m = 1; m < 16; m <<= 1)
#pragma unroll
    for (int r = 0; r < 4; ++r) rmax[r] = fmaxf(rmax[r], __shfl_xor(rmax[r], m));
  float rsum[4] = {0.f, 0.f, 0.f, 0.f};
#pragma unroll
  for (int ct = 0; ct < 14; ++ct)
#pragma unroll
    for (int r = 0; r < 4; ++r) {
      float e = __expf(acc[ct][r] - rmax[r]);
      acc[ct][r] = e;
      rsum[r] += e;
    }
#pragma unroll
  for (int m = 1; m < 16; m <<= 1)
#pragma unroll
    for (int r = 0; r < 4; ++r) rsum[r] += __shfl_xor(rsum[r], m);
  float rinv[4];
#pragma unroll
  for (int r = 0; r < 4; ++r) rinv[r] = 1.f / rsum[r];

  __syncthreads();

#pragma unroll
  for (int ct = 0; ct < 14; ++ct)
#pragma unroll
    for (int r = 0; r < 4; ++r) {
      int prow = wv * 16 + quad * 4 + r;
      ldsKP[prow * 232 + ct * 16 + l16] = f2bf(acc[ct][r] * rinv[r]);
    }
  __syncthreads();

  f32x4 oacc[4];
#pragma unroll
  for (int ot = 0; ot < 4; ++ot) oacc[ot] = (f32x4){0.f, 0.f, 0.f, 0.f};
#pragma unroll
  for (int kc = 0; kc < 7; ++kc) {
    short8 ap = *(const short8*)&ldsKP[(wv * 16 + l16) * 232 + kc * 32 + quad * 8];
    int keybase = kc * 32 + quad * 8;
#pragma unroll
    for (int ot = 0; ot < 4; ++ot) {
      int dcol = ot * 16 + l16;
      short8 bv;
#pragma unroll
      for (int j = 0; j < 8; ++j) bv[j] = (short)ldsV[(keybase + j) * 72 + dcol];
      oacc[ot] = __builtin_amdgcn_mfma_f32_16x16x32_bf16(ap, bv, oacc[ot], 0, 0, 0);
    }
  }

#pragma unroll
  for (int ot = 0; ot < 4; ++ot)
#pragma unroll
    for (int r = 0; r < 4; ++r) {
      int rowg = chunk * 64 + wv * 16 + quad * 4 + r;
      if (rowg < ND)
        o[((size_t)b * ND + rowg) * 128 + h * 64 + ot * 16 + l16] = oacc[ot][r];
    }
}

// ---------------------------------------------------------------------------
// K8: bilinear grid-sample of pos_embed at pos_down, accumulate into out
// ---------------------------------------------------------------------------
__global__ __launch_bounds__(256) void k_posfeat(const float* __restrict__ pd,
    const float* __restrict__ pe, float* __restrict__ out) {
  int t = blockIdx.x * 256 + threadIdx.x;
  int row = t >> 5, lane = t & 31;
  if (row >= B_ * ND) return;
  float gx = pd[(size_t)2*row] * 2.f - 1.f;
  float gy = pd[(size_t)2*row+1] * 2.f - 1.f;
  float ix = ((gx + 1.f) * 56.f - 1.f) * 0.5f;
  float iy = ((gy + 1.f) * 56.f - 1.f) * 0.5f;
  float x0 = floorf(ix), y0 = floorf(iy);
  float wx1 = ix - x0, wy1 = iy - y0;
  float wx0 = 1.f - wx1, wy0 = 1.f - wy1;
  float4 acc = make_float4(0.f, 0.f, 0.f, 0.f);
#pragma unroll
  for (int cy = 0; cy < 2; ++cy) {
#pragma unroll
    for (int cx = 0; cx < 2; ++cx) {
      float xc = x0 + (float)cx, yc = y0 + (float)cy;
      float wgt = (cx ? wx1 : wx0) * (cy ? wy1 : wy0);
      bool valid = (xc >= 0.f) && (xc < 56.f) && (yc >= 0.f) && (yc < 56.f);
      if (valid) {
        int lin = (int)yc * 56 + (int)xc;
        float4 pv = ((const float4*)(pe + (size_t)lin * 128))[lane];
        acc.x += wgt * pv.x; acc.y += wgt * pv.y;
        acc.z += wgt * pv.z; acc.w += wgt * pv.w;
      }
    }
  }
  float4* op = (float4*)(out + (size_t)row * 128) + lane;
  float4 cur = *op;
  cur.x += acc.x; cur.y += acc.y; cur.z += acc.z; cur.w += acc.w;
  *op = cur;
}

// ---------------------------------------------------------------------------
// launcher
// ---------------------------------------------------------------------------
extern "C" void kernel_launch(void* const* d_in, const int* in_sizes, int n_in,
                              void* d_out, int out_size, void* d_ws, size_t ws_size,
                              hipStream_t stream) {
  const float* x      = (const float*)d_in[0];
  const float* pos    = (const float*)d_in[1];
  const float* pe     = (const float*)d_in[2];
  const float* nu     = (const float*)d_in[3];
  const float* norm_g = (const float*)d_in[4];
  const float* norm_b = (const float*)d_in[5];
  const float* conf_w = (const float*)d_in[6];
  const float* conf_b = (const float*)d_in[7];
  const float* n1g    = (const float*)d_in[8];
  const float* n1b    = (const float*)d_in[9];
  const float* q_w    = (const float*)d_in[10];
  const float* k_w    = (const float*)d_in[11];
  const float* v_w    = (const float*)d_in[12];
  const float* proj_w = (const float*)d_in[13];
  const float* proj_b = (const float*)d_in[14];
  const float* sr_w   = (const float*)d_in[15];
  const float* sr_b   = (const float*)d_in[16];
  const float* srn_g  = (const float*)d_in[17];
  const float* srn_b  = (const float*)d_in[18];
  const float* fc_w   = (const float*)d_in[19];
  const float* fc_b   = (const float*)d_in[20];
  const float* n2g    = (const float*)d_in[21];
  const float* n2b    = (const float*)d_in[22];
  const float* fc1_w  = (const float*)d_in[23];
  const float* fc1_b  = (const float*)d_in[24];
  const float* fc2_w  = (const float*)d_in[25];
  const float* fc2_b  = (const float*)d_in[26];

  char* ws = (char*)d_ws;
  // workspace layout (bytes); total 190,578,688 (unchanged)
  double*         scores = (double*)(ws + 0);                //  1,580,544
  int*            idx    = (int*)(ws + 1605632);             //    200,704
  float*          xd     = (float*)(ws + 1835008);           // 13,647,872
  float*          xn     = (float*)(ws + 15728640);          // 13,647,872
  float*          pd     = (float*)(ws + 29491200);          //    426,496
  float*          qb     = (float*)(ws + 30408704);          // 27,295,744; T alias; later q/O2
  float*          ob     = (float*)(ws + 58720256);          // 27,295,744; T tail alias; later xn2
  float*          wt     = (float*)(ws + 86507520);          //    262,144
  unsigned short* W1p    = (unsigned short*)(ws + 86769664); //    131,072
  unsigned short* W2p    = (unsigned short*)(ws + 86900736); //    131,072 (ends 87,031,808)
  char*           big    = ws + 87031808;                    // 103,546,880 region
  float*          S      = (float*)big;                      // 52,183,040 (dead after transpose)
  float*          T      = qb;                               // 51,380,224 channel planes (dead after filter2)
  float*          Kc     = (float*)(big + 52183040);         //  7,225,344 coefficient planes (dead after filter2)
  float*          P      = (float*)big;                      // 51,380,224 (reuses dead S; dead after conv)
  float*          xs_c   = (float*)(big + 59408384);         //  3,211,264
  float*          xs_n   = (float*)(big + 62619648);         //  3,211,264
  float*          kbuf   = (float*)(big + 65830912);         //  6,422,528
  float*          vbuf   = (float*)(big + 72253440);         //  6,422,528 (ends 78,675,968)
  float*          Mbuf   = (float*)(big + 78675968);         //    802,816 mask plane (dead after coef)
  float*          O2     = qb;
  float*          xn2    = ob;
  float*          out    = (float*)d_out;

  // 1) f64 conf+gumbel scores
  k_conf<<<(B_ * N_) / 256, 256, 0, stream>>>(x, norm_g, norm_b, conf_w, conf_b, nu, scores);
  // 2) top-784 per batch: exact counting-sort rank (one block per batch)
  k_topk2<<<B_, 256, 0, stream>>>(scores, idx);
  // 3) gather + LN(norm1)
  k_gather_ln<<<(B_ * ND + 255) / 256, 256, 0, stream>>>(x, pos, idx, n1g, n1b, xd, xn, pd);
  // 4) token2map scatter (wave-per-token, coalesced atomics, f64 binning)
  hipMemsetAsync(S, 0, (size_t)B_ * HW * 65 * sizeof(float), stream);
  k_scatter<<<(B_ * N_ * 64) / 256, 256, 0, stream>>>(x, n1g, n1b, pos, S);
  // 5) gaussian reconstruct: transpose (+mask plane), coef (coalesced mask),
  //    spatially-varying 3x3 conv
  k_transpose<<<BHW / 64, 256, 0, stream>>>(S, T, Mbuf);
  k_coef<<<BHW / 256, 256, 0, stream>>>(Mbuf, Kc);
  k_filter2<<<B_ * 64, 256, 0, stream>>>(T, Kc, P);
  // 6) conv weights transpose + MLP weight pack; conv-as-GEMM; srnorm
  k_wt<<<(1024 * 64) / 256, 256, 0, stream>>>(sr_w, wt);
  k_wpack<<<65536 / 256, 256, 0, stream>>>(fc1_w, fc2_w, W1p, W2p);
  dim3 g_conv(NS * B_ / 64, 1);
  k_gemm<<<g_conv, 256, 0, stream>>>(P, wt, sr_b, nullptr, xs_c, B_ * NS, 64, 1024);
  k_ln64<<<(B_ * NS + 255) / 256, 256, 0, stream>>>(xs_c, srn_g, srn_b, xs_n, B_ * NS);
  // 7) k, v, q projections (q GEMM overwrites T region -- T is dead by now)
  dim3 g_kv(B_ * NS / 64, 2);
  k_gemm<<<g_kv, 256, 0, stream>>>(xs_n, k_w, nullptr, nullptr, kbuf, B_ * NS, 128, 64);
  k_gemm<<<g_kv, 256, 0, stream>>>(xs_n, v_w, nullptr, nullptr, vbuf, B_ * NS, 128, 64);
  dim3 g_row(B_ * ND / 64, 2);
  k_gemm<<<g_row, 256, 0, stream>>>(xn, q_w, nullptr, nullptr, qb, B_ * ND, 128, 64);
  // 8) attention (MFMA bf16)
  k_attn<<<B_ * 2 * 14, 256, 0, stream>>>(qb, kbuf, vbuf, ob);
  // 9) x2 = x_down@fc_w + fc_b + (o@proj_w + proj_b)  -> d_out
  k_gemm<<<g_row, 256, 0, stream>>>(ob, proj_w, proj_b, nullptr, O2, B_ * ND, 128, 128);
  k_gemm<<<g_row, 256, 0, stream>>>(xd, fc_w, fc_b, O2, out, B_ * ND, 128, 64);
  // 10) MLP: LN128 then MFMA fused fc1+gelu+fc2 (accumulates into out)
  k_ln128<<<(B_ * ND + 255) / 256, 256, 0, stream>>>(out, n2g, n2b, xn2, B_ * ND);
  k_mlp<<<B_ * ND / 64, 256, 0, stream>>>(xn2, W1p, fc1_b, W2p, fc2_b, out);
  // 11) + pos_feat (bilinear grid sample)
  k_posfeat<<<(B_ * ND * 32) / 256, 256, 0, stream>>>(pd, pe, out);
}